// Round 7
// baseline (205.749 us; speedup 1.0000x reference)
//
#include <hip/hip_runtime.h>

// GQA causal+segment-masked flash attention. fp32 in/out.
// B=2, T=2048, NQ=32 (8 kv heads x 4), D=128.
// R14: arithmetic-intensity round. R13 evidence: FETCH halved with zero
// dur change; per-wave-tile cost invariant ~1050cyc across 5 structures;
// occupancy insensitive -> per-CU VMEM return BW is the wall (~88 B/cyc,
// 16KB per wave-tile). Fix: 32 q-rows per wave (two 16-row groups share
// each K/V tile load) -> wave-tiles 272K->133K, VMEM bytes halved.
// 4 independent waves/block (q-heads of one kvh), no LDS, no barriers.
// Keeps: swapped QK mfma(K,Q), in-register P transpose (cvt_pk_bf16 +
// permlane16/32_swap), unnormalized exp2 accum, folded causal pairing.

typedef __bf16 bf16x8 __attribute__((ext_vector_type(8)));
typedef __bf16 bf16x2 __attribute__((ext_vector_type(2)));
typedef _Float16 f16x8 __attribute__((ext_vector_type(8)));
typedef float f32x4 __attribute__((ext_vector_type(4)));
typedef unsigned int uint2v __attribute__((ext_vector_type(2)));

#define B_   2
#define T_   2048
#define NQ_  32
#define NKV_ 8
#define D_   128

#define MASKV (-3.0e38f)
#define LOG2E 1.44269504f
#define TILE_US 8192           // ushorts per 32-col KV tile in ws: 8KB fp16 K + 8KB bf16 Vt
#define WS_TILES_BYTES ((size_t)B_ * NKV_ * (T_ / 32) * TILE_US * 2)   // 16777216
#define WS_NEED (WS_TILES_BYTES + (size_t)B_ * T_ * 4)

static __device__ __forceinline__ unsigned short f2bf(float x) {
    union { float f; unsigned int u; } c; c.f = x;
    unsigned int r = c.u + 0x7fffu + ((c.u >> 16) & 1u);
    return (unsigned short)(r >> 16);
}

union U8  { unsigned short us[8]; bf16x8 v; };
union H8  { _Float16 h[8]; f16x8 v; };
union PKW { bf16x2 h; unsigned int u; };
union PA4 { unsigned int u[4]; bf16x8 v; };

// register-pair lane swaps (gfx950): a[32:63] <-> b[0:31]  /  a[16:31]<->b[0:15], a[48:63]<->b[32:47]
static __device__ __forceinline__ void pl32swap(unsigned int& a, unsigned int& b) {
#if __has_builtin(__builtin_amdgcn_permlane32_swap)
    uint2v t = __builtin_amdgcn_permlane32_swap(a, b, false, false);
    a = t.x; b = t.y;
#else
    asm("s_nop 1\n\tv_permlane32_swap_b32 %0, %1" : "+v"(a), "+v"(b));
#endif
}
static __device__ __forceinline__ void pl16swap(unsigned int& a, unsigned int& b) {
#if __has_builtin(__builtin_amdgcn_permlane16_swap)
    uint2v t = __builtin_amdgcn_permlane16_swap(a, b, false, false);
    a = t.x; b = t.y;
#else
    asm("s_nop 1\n\tv_permlane16_swap_b32 %0, %1" : "+v"(a), "+v"(b));
#endif
}

// ---------------- prep 1: K -> fp16, V^T -> bf16, fragment-ordered ws tiles ----------------
// K region (ushort 0..4095):  16B slot = (c*2+hi)*64 + qd*16 + ln
//   holds K[row = hi*16+ln][d = c*32+qd*8 .. +7] as fp16.
// V region (ushort 4096..8191): 16B slot = sub*64 + sc*16 + dln
//   holds V^T[d = sub*16+dln][kv = sc*8 .. +7] as bf16.
__global__ __launch_bounds__(256)
void prep(const float* __restrict__ kg, const float* __restrict__ vg,
          unsigned short* __restrict__ ws)
{
    const int tid = threadIdx.x;
    const int st  = blockIdx.x;    // 32-col KV tile index
    const int kvh = blockIdx.y;
    const int b   = blockIdx.z;
    unsigned short* base = ws + ((size_t)((b * NKV_ + kvh) * (T_ / 32) + st)) * TILE_US;

    // K: 512 tasks = 32 rows x 16 chunks(8 elems), fp16
    #pragma unroll
    for (int it = 0; it < 2; ++it) {
        int task = tid + it * 256;
        int r = task >> 4, c16 = task & 15;            // d = c16*8
        const float* kp = kg + (((size_t)(b * T_ + st * 32 + r)) * NKV_ + kvh) * D_ + c16 * 8;
        H8 hu;
        #pragma unroll
        for (int j = 0; j < 8; ++j) hu.h[j] = (_Float16)kp[j];
        int c = c16 >> 2, qd = c16 & 3, hi = r >> 4, ln = r & 15;
        int slot = (c * 2 + hi) * 64 + qd * 16 + ln;
        *(f16x8*)(base + slot * 8) = hu.v;
    }
    // V^T: 512 tasks = 128 d x 4 s-chunks(8 s), bf16
    #pragma unroll
    for (int it = 0; it < 2; ++it) {
        int task = tid + it * 256;
        int d = task & 127, sc = task >> 7;
        const float* vp = vg + (((size_t)(b * T_ + st * 32 + sc * 8)) * NKV_ + kvh) * D_ + d;
        U8 pk;
        #pragma unroll
        for (int j = 0; j < 8; ++j) pk.us[j] = f2bf(vp[j * (NKV_ * D_)]);
        int slot = (d >> 4) * 64 + sc * 16 + (d & 15);
        *(bf16x8*)(base + 4096 + slot * 8) = pk.v;
    }
}

// ---------------- prep 2: per-row segment start indices ----------------
__global__ __launch_bounds__(256)
void prep_sstart(const int* __restrict__ seg, int* __restrict__ sstart)
{
    int idx = blockIdx.x * 256 + threadIdx.x;
    int b = idx >> 11, t = idx & (T_ - 1);
    const int* sb = seg + b * T_;
    int target = sb[t];
    int lo = 0, hi = t;
    while (lo < hi) { int mid = (lo + hi) >> 1; if (sb[mid] < target) lo = mid + 1; else hi = mid; }
    sstart[idx] = lo;
}

// ---------------- main attention kernel (4 independent waves/block, 32 q-rows/wave) ----------------
__global__ __launch_bounds__(256)
void attn_fwd(const float* __restrict__ qg,
              const int* __restrict__ sstart,
              const unsigned short* __restrict__ ws,
              float* __restrict__ outg)
{
    const int tid  = threadIdx.x;
    const int wave = tid >> 6;
    const int lane = tid & 63;
    const int qd   = lane >> 4;
    const int ln   = lane & 15;

    const int kvh  = blockIdx.x;             // kv head; 4 waves = its 4 q-heads
    const int head = kvh * 4 + wave;
    const int j    = blockIdx.y;             // folded pair index 0..31 over 64 chunks
    const int b    = blockIdx.z;

    const unsigned short* wsbase =
        ws + ((size_t)((b * NKV_ + kvh) * (T_ / 32))) * TILE_US + lane * 8;

    // load K(tile) and V(tile) fragments into named register buffers (16 KB/wave)
#define LOADKV(KB, VB, tl) do {                                                \
        const unsigned short* _tb = wsbase + (size_t)(tl) * TILE_US;           \
        _Pragma("unroll")                                                      \
        for (int _c = 0; _c < 4; ++_c) {                                       \
            KB[_c][0] = *(const f16x8*)(_tb + (_c * 2 + 0) * 512);             \
            KB[_c][1] = *(const f16x8*)(_tb + (_c * 2 + 1) * 512);             \
        }                                                                      \
        _Pragma("unroll")                                                      \
        for (int _s = 0; _s < 8; ++_s)                                         \
            VB[_s] = *(const bf16x8*)(_tb + 4096 + _s * 512);                  \
    } while (0)

    // One 16-row group: swapped QK -> mask -> exp2 -> in-reg transpose -> PV.
    // Lane(qd,ln): S[kv=_s0+qd*4+r (+16)][qrow=ln].
#define QKPV(QH, QL, OO, LL, RS_L, TROW_L, KB, VB, FAST) do {                  \
        f32x4 S0 = {0.f,0.f,0.f,0.f}, S1 = {0.f,0.f,0.f,0.f};                  \
        __builtin_amdgcn_s_setprio(1);                                         \
        _Pragma("unroll")                                                      \
        for (int c = 0; c < 4; ++c) {                                          \
            S0 = __builtin_amdgcn_mfma_f32_16x16x32_f16(KB[c][0], QH[c], S0,0,0,0); \
            S1 = __builtin_amdgcn_mfma_f32_16x16x32_f16(KB[c][1], QH[c], S1,0,0,0); \
            S0 = __builtin_amdgcn_mfma_f32_16x16x32_f16(KB[c][0], QL[c], S0,0,0,0); \
            S1 = __builtin_amdgcn_mfma_f32_16x16x32_f16(KB[c][1], QL[c], S1,0,0,0); \
        }                                                                      \
        __builtin_amdgcn_s_setprio(0);                                         \
        float p0[4], p1[4];                                                    \
        if (FAST) {                                                            \
            _Pragma("unroll")                                                  \
            for (int r = 0; r < 4; ++r) {                                      \
                p0[r] = exp2f(S0[r]);                                          \
                p1[r] = exp2f(S1[r]);                                          \
            }                                                                  \
        } else {                                                               \
            _Pragma("unroll")                                                  \
            for (int r = 0; r < 4; ++r) {                                      \
                int kv0 = _s0 + qd * 4 + r;                                    \
                int kv1 = kv0 + 16;                                            \
                float sv0 = (kv0 >= (RS_L) && kv0 <= (TROW_L)) ? S0[r] : MASKV;\
                float sv1 = (kv1 >= (RS_L) && kv1 <= (TROW_L)) ? S1[r] : MASKV;\
                p0[r] = exp2f(sv0);                                            \
                p1[r] = exp2f(sv1);                                            \
            }                                                                  \
        }                                                                      \
        LL += (p0[0] + p0[1]) + (p0[2] + p0[3])                                \
            + (p1[0] + p1[1]) + (p1[2] + p1[3]);                               \
        PKW c0, c1, c2, c3;                                                    \
        c0.h = (bf16x2){(__bf16)p0[0], (__bf16)p0[1]};                         \
        c1.h = (bf16x2){(__bf16)p0[2], (__bf16)p0[3]};                         \
        c2.h = (bf16x2){(__bf16)p1[0], (__bf16)p1[1]};                         \
        c3.h = (bf16x2){(__bf16)p1[2], (__bf16)p1[3]};                         \
        unsigned int w0 = c0.u, w1 = c1.u, w2 = c2.u, w3 = c3.u;               \
        pl32swap(w0, w2); pl32swap(w1, w3);                                    \
        pl16swap(w0, w2); pl16swap(w1, w3);                                    \
        PA4 pw; pw.u[0] = w0; pw.u[1] = w1; pw.u[2] = w2; pw.u[3] = w3;        \
        bf16x8 pa = pw.v;                                                      \
        __builtin_amdgcn_s_setprio(1);                                         \
        _Pragma("unroll")                                                      \
        for (int sub = 0; sub < 8; ++sub)                                      \
            OO[sub] = __builtin_amdgcn_mfma_f32_16x16x32_bf16(pa, VB[sub], OO[sub],0,0,0); \
        __builtin_amdgcn_s_setprio(0);                                         \
    } while (0)

    // Both 16-row groups against one K/V tile (loads amortized 2x)
#define COMPUTE(KB, VB, TL) do {                                               \
        const int _s0 = (TL) * 32;                                             \
        const bool fastall = (_s0 >= wave_rs_max) && (_s0 + 31 <= t0);         \
        QKPV(qh0, ql0, O0, l0, rs0_l, trow0_l, KB, VB, fastall);               \
        QKPV(qh1, ql1, O1, l1, rs1_l, trow1_l, KB, VB, fastall);               \
    } while (0)

    // Folded pair: phase 0 = heavy 32-row chunk (63-j), phase 1 = light (j).
    for (int phase = 0; phase < 2; ++phase) {
        const int chunk = (phase == 0) ? (2 * (int)gridDim.y - 1 - j) : j;
        const int t0 = chunk * 32;

        // ---- preload Q fragments for both groups, scaled by log2(e), fp16 hi/lo ----
        f16x8 qh0[4], ql0[4], qh1[4], ql1[4];
        #pragma unroll
        for (int g = 0; g < 2; ++g) {
            const float* qrow =
                qg + (((size_t)(b * T_ + (t0 + g * 16 + ln)) * NQ_) + head) * D_;
            #pragma unroll
            for (int c = 0; c < 4; ++c) {
                float4 a  = *(const float4*)(qrow + c * 32 + qd * 8);
                float4 b2 = *(const float4*)(qrow + c * 32 + qd * 8 + 4);
                float xs[8] = {a.x, a.y, a.z, a.w, b2.x, b2.y, b2.z, b2.w};
                H8 hu, lu;
                #pragma unroll
                for (int jj = 0; jj < 8; ++jj) {
                    float x = xs[jj] * LOG2E;
                    _Float16 h = (_Float16)x;
                    hu.h[jj] = h;
                    lu.h[jj] = (_Float16)(x - (float)h);
                }
                if (g == 0) { qh0[c] = hu.v; ql0[c] = lu.v; }
                else        { qh1[c] = hu.v; ql1[c] = lu.v; }
            }
        }

        // ---- per-lane row info for both groups ----
        const int trow0_l = t0 + ln;
        const int trow1_l = t0 + 16 + ln;
        const int rs0_l   = sstart[b * T_ + trow0_l];
        const int rs1_l   = sstart[b * T_ + trow1_l];
        const int wave_rs_max = sstart[b * T_ + t0 + 31];   // sorted -> max of 32 rows

        const int tile0   = sstart[b * T_ + t0] >> 5;       // wave-uniform (min row)
        const int n_tiles = chunk + 1;                      // causal: kv tiles 0..chunk

        f32x4 O0[8], O1[8];
        #pragma unroll
        for (int k = 0; k < 8; ++k) {
            O0[k] = (f32x4){0.f, 0.f, 0.f, 0.f};
            O1[k] = (f32x4){0.f, 0.f, 0.f, 0.f};
        }
        float l0 = 0.f, l1 = 0.f;

        f16x8  kA[4][2], kB_[4][2];
        bf16x8 vA[8], vB_[8];

        int t = tile0;
        LOADKV(kA, vA, t);                      // prologue
        while (t + 1 < n_tiles) {
            LOADKV(kB_, vB_, t + 1);            // prefetch under compute(A)
            COMPUTE(kA, vA, t);
            if (t + 2 < n_tiles) LOADKV(kA, vA, t + 2);
            COMPUTE(kB_, vB_, t + 1);
            t += 2;
        }
        if (t < n_tiles) COMPUTE(kA, vA, t);

        // ---- epilogue per group: reduce l across qd, redistribute, store ----
        #pragma unroll
        for (int g = 0; g < 2; ++g) {
            float l = (g == 0) ? l0 : l1;
            l += __shfl_xor(l, 16);
            l += __shfl_xor(l, 32);
            const float invl = 1.0f / l;        // per lane: denom for q-row = g*16+ln
            int trow[4];
            float inv[4];
            #pragma unroll
            for (int r = 0; r < 4; ++r) {
                trow[r] = t0 + g * 16 + qd * 4 + r;
                inv[r]  = __shfl(invl, qd * 4 + r);  // lane (qd*4+r) holds row's denom
            }
            #pragma unroll
            for (int sub = 0; sub < 8; ++sub) {
                #pragma unroll
                for (int r = 0; r < 4; ++r) {
                    float ov = (g == 0) ? O0[sub][r] : O1[sub][r];
                    outg[(((size_t)(b * T_ + trow[r]) * NQ_) + head) * D_ + sub * 16 + ln] =
                        ov * inv[r];
                }
            }
        }
    }

#undef LOADKV
#undef QKPV
#undef COMPUTE
}

// ---------------- fallback (no-ws path) ----------------
#define KSTR 136
#define VSTR 40
#define PSTR 40
static __device__ __forceinline__ float bf2f(unsigned short h) {
    union { unsigned int u; float f; } c; c.u = (unsigned int)h << 16; return c.f;
}
__global__ __launch_bounds__(256)
void attn_fwd_fb(const float* __restrict__ qg,
                 const float* __restrict__ kg,
                 const float* __restrict__ vg,
                 const int* __restrict__ seg,
                 float* __restrict__ outg)
{
    __shared__ unsigned short sKh[32 * KSTR];
    __shared__ unsigned short sKl[32 * KSTR];
    __shared__ unsigned short sVt[128 * VSTR];
    __shared__ unsigned short sP[4][16 * PSTR];

    const int tid  = threadIdx.x;
    const int wave = tid >> 6;
    const int lane = tid & 63;
    const int qd   = lane >> 4;
    const int ln   = lane & 15;
    const int t0   = ((int)gridDim.x - 1 - (int)blockIdx.x) * 64;
    const int head = blockIdx.y;
    const int kvh  = head >> 2;
    const int b    = blockIdx.z;

    bf16x8 qh[4], ql[4];
    {
        const float* qrow =
            qg + (((size_t)(b * T_ + (t0 + wave * 16 + ln)) * NQ_) + head) * D_;
        #pragma unroll
        for (int c = 0; c < 4; ++c) {
            float4 a  = *(const float4*)(qrow + c * 32 + qd * 8);
            float4 b2 = *(const float4*)(qrow + c * 32 + qd * 8 + 4);
            float xs[8] = {a.x, a.y, a.z, a.w, b2.x, b2.y, b2.z, b2.w};
            U8 hu, lu;
            #pragma unroll
            for (int j = 0; j < 8; ++j) {
                unsigned short h = f2bf(xs[j]);
                hu.us[j] = h;
                lu.us[j] = f2bf(xs[j] - bf2f(h));
            }
            qh[c] = hu.v; ql[c] = lu.v;
        }
    }
    const int* sb = seg + (size_t)b * T_;
    int qseg[4];
    #pragma unroll
    for (int r = 0; r < 4; ++r) qseg[r] = sb[t0 + wave * 16 + qd * 4 + r];
    int tile0;
    {
        int target = sb[t0];
        int lo = 0, hi = t0;
        while (lo < hi) { int mid = (lo + hi) >> 1; if (sb[mid] < target) lo = mid + 1; else hi = mid; }
        tile0 = lo >> 5;
    }
    f32x4 O[8];
    #pragma unroll
    for (int i = 0; i < 8; ++i) O[i] = (f32x4){0.f, 0.f, 0.f, 0.f};
    float m_prev[4], l_lane[4];
    #pragma unroll
    for (int r = 0; r < 4; ++r) { m_prev[r] = MASKV; l_lane[r] = 0.f; }
    const int n_tiles = t0 / 32 + 2;

    for (int tile = tile0; tile < n_tiles; ++tile) {
        const int s0 = tile * 32;
        __syncthreads();
        #pragma unroll
        for (int it = 0; it < 2; ++it) {
            int task = tid + it * 256;
            int r = task >> 4, d = (task & 15) * 8;
            const float* kp = kg + (((size_t)(b * T_ + s0 + r) * NKV_) + kvh) * D_ + d;
            float4 a  = *(const float4*)(kp);
            float4 b2 = *(const float4*)(kp + 4);
            float xs[8] = {a.x, a.y, a.z, a.w, b2.x, b2.y, b2.z, b2.w};
            U8 hu, lu;
            #pragma unroll
            for (int j = 0; j < 8; ++j) {
                unsigned short h = f2bf(xs[j]);
                hu.us[j] = h;
                lu.us[j] = f2bf(xs[j] - bf2f(h));
            }
            *(bf16x8*)(sKh + r * KSTR + d) = hu.v;
            *(bf16x8*)(sKl + r * KSTR + d) = lu.v;
        }
        #pragma unroll
        for (int it = 0; it < 2; ++it) {
            int task = tid + it * 256;
            int d = task & 127, sg = task >> 7;
            const float* vp = vg + (((size_t)(b * T_ + s0 + sg * 8) * NKV_) + kvh) * D_ + d;
            U8 pk;
            #pragma unroll
            for (int j = 0; j < 8; ++j) pk.us[j] = f2bf(vp[j * (NKV_ * D_)]);
            *(bf16x8*)(sVt + d * VSTR + sg * 8) = pk.v;
        }
        __syncthreads();

        f32x4 S0 = {0.f,0.f,0.f,0.f}, S1 = {0.f,0.f,0.f,0.f};
        #pragma unroll
        for (int c = 0; c < 4; ++c) {
            bf16x8 kh0 = *(const bf16x8*)(sKh + ln * KSTR + c * 32 + qd * 8);
            bf16x8 kh1 = *(const bf16x8*)(sKh + (16 + ln) * KSTR + c * 32 + qd * 8);
            bf16x8 kl0 = *(const bf16x8*)(sKl + ln * KSTR + c * 32 + qd * 8);
            bf16x8 kl1 = *(const bf16x8*)(sKl + (16 + ln) * KSTR + c * 32 + qd * 8);
            S0 = __builtin_amdgcn_mfma_f32_16x16x32_bf16(qh[c], kh0, S0, 0, 0, 0);
            S1 = __builtin_amdgcn_mfma_f32_16x16x32_bf16(qh[c], kh1, S1, 0, 0, 0);
            S0 = __builtin_amdgcn_mfma_f32_16x16x32_bf16(qh[c], kl0, S0, 0, 0, 0);
            S1 = __builtin_amdgcn_mfma_f32_16x16x32_bf16(qh[c], kl1, S1, 0, 0, 0);
            S0 = __builtin_amdgcn_mfma_f32_16x16x32_bf16(ql[c], kh0, S0, 0, 0, 0);
            S1 = __builtin_amdgcn_mfma_f32_16x16x32_bf16(ql[c], kh1, S1, 0, 0, 0);
        }
        const int ks0 = sb[s0 + ln];
        const int ks1 = sb[s0 + 16 + ln];
        float p0[4], p1[4], alpha[4];
        #pragma unroll
        for (int r = 0; r < 4; ++r) {
            const int trow = t0 + wave * 16 + qd * 4 + r;
            float s0v = ((s0 + ln <= trow) && (ks0 == qseg[r])) ? S0[r] : MASKV;
            float s1v = ((s0 + 16 + ln <= trow) && (ks1 == qseg[r])) ? S1[r] : MASKV;
            float mx = fmaxf(s0v, s1v);
            mx = fmaxf(mx, __shfl_xor(mx, 1));
            mx = fmaxf(mx, __shfl_xor(mx, 2));
            mx = fmaxf(mx, __shfl_xor(mx, 4));
            mx = fmaxf(mx, __shfl_xor(mx, 8));
            const float mn = fmaxf(m_prev[r], mx);
            alpha[r] = __expf(m_prev[r] - mn);
            p0[r] = __expf(s0v - mn);
            p1[r] = __expf(s1v - mn);
            l_lane[r] = alpha[r] * l_lane[r] + p0[r] + p1[r];
            m_prev[r] = mn;
        }
        #pragma unroll
        for (int i = 0; i < 8; ++i) {
            O[i][0] *= alpha[0]; O[i][1] *= alpha[1];
            O[i][2] *= alpha[2]; O[i][3] *= alpha[3];
        }
        {
            unsigned short* pw = sP[wave] + (qd * 4) * PSTR + ln;
            #pragma unroll
            for (int r = 0; r < 4; ++r) {
                pw[r * PSTR]      = f2bf(p0[r]);
                pw[r * PSTR + 16] = f2bf(p1[r]);
            }
        }
        asm volatile("s_waitcnt lgkmcnt(0)" ::: "memory");
        bf16x8 pa = *(const bf16x8*)(sP[wave] + ln * PSTR + qd * 8);
        #pragma unroll
        for (int sub = 0; sub < 8; ++sub) {
            bf16x8 bv = *(const bf16x8*)(sVt + (sub * 16 + ln) * VSTR + qd * 8);
            O[sub] = __builtin_amdgcn_mfma_f32_16x16x32_bf16(pa, bv, O[sub], 0, 0, 0);
        }
    }
    float inv[4];
    #pragma unroll
    for (int r = 0; r < 4; ++r) {
        float l = l_lane[r];
        l += __shfl_xor(l, 1);
        l += __shfl_xor(l, 2);
        l += __shfl_xor(l, 4);
        l += __shfl_xor(l, 8);
        inv[r] = 1.0f / l;
    }
    #pragma unroll
    for (int sub = 0; sub < 8; ++sub) {
        #pragma unroll
        for (int r = 0; r < 4; ++r) {
            const int trow = t0 + wave * 16 + qd * 4 + r;
            outg[(((size_t)(b * T_ + trow) * NQ_) + head) * D_ + sub * 16 + ln] =
                O[sub][r] * inv[r];
        }
    }
}

extern "C" void kernel_launch(void* const* d_in, const int* in_sizes, int n_in,
                              void* d_out, int out_size, void* d_ws, size_t ws_size,
                              hipStream_t stream) {
    const float* q  = (const float*)d_in[0];
    const float* k  = (const float*)d_in[1];
    const float* v  = (const float*)d_in[2];
    const int*   sg = (const int*)d_in[3];
    float*       o  = (float*)d_out;
    if (ws_size >= WS_NEED) {
        unsigned short* ws = (unsigned short*)d_ws;
        int* sstart = (int*)((char*)d_ws + WS_TILES_BYTES);
        prep<<<dim3(T_ / 32, NKV_, B_), dim3(256), 0, stream>>>(k, v, ws);
        prep_sstart<<<dim3(B_ * T_ / 256), dim3(256), 0, stream>>>(sg, sstart);
        attn_fwd<<<dim3(NKV_, T_ / 64, B_), dim3(256), 0, stream>>>(q, sstart, ws, o);
    } else {
        attn_fwd_fb<<<dim3(T_ / 64, NQ_, B_), dim3(256), 0, stream>>>(q, k, v, sg, o);
    }
}

// Round 8
// 190.957 us; speedup vs baseline: 1.0775x; 1.0775x over previous
//
#include <hip/hip_runtime.h>

// GQA causal+segment-masked flash attention. fp32 in/out.
// B=2, T=2048, NQ=32 (8 kv heads x 4), D=128.
// R15: R14's 32-q-rows-per-wave body (halves L1-return bytes per unit
// work; R13 was L1-BW bound: 128 of 182 cyc/wave-tile was 16KB/128B
// return occupancy) + R13's parallelism restored: UNFOLDED grid
// (8 kvh, 64 chunks, 2) = 1024 workgroups of 4 independent waves
// (one per q-head, same chunk -> shared KV stream). Heavy-first chunk
// order; dynamic backfill balances causal skew. prep_sstart merged into
// prep (one fewer serialized launch). No LDS, no barriers. Keeps:
// swapped QK mfma(K,Q), in-register P transpose (cvt_pk_bf16 +
// permlane16/32_swap), unnormalized exp2 accum, setprio.

typedef __bf16 bf16x8 __attribute__((ext_vector_type(8)));
typedef __bf16 bf16x2 __attribute__((ext_vector_type(2)));
typedef _Float16 f16x8 __attribute__((ext_vector_type(8)));
typedef float f32x4 __attribute__((ext_vector_type(4)));
typedef unsigned int uint2v __attribute__((ext_vector_type(2)));

#define B_   2
#define T_   2048
#define NQ_  32
#define NKV_ 8
#define D_   128

#define MASKV (-3.0e38f)
#define LOG2E 1.44269504f
#define TILE_US 8192           // ushorts per 32-col KV tile in ws: 8KB fp16 K + 8KB bf16 Vt
#define WS_TILES_BYTES ((size_t)B_ * NKV_ * (T_ / 32) * TILE_US * 2)   // 16777216
#define WS_NEED (WS_TILES_BYTES + (size_t)B_ * T_ * 4)

static __device__ __forceinline__ unsigned short f2bf(float x) {
    union { float f; unsigned int u; } c; c.f = x;
    unsigned int r = c.u + 0x7fffu + ((c.u >> 16) & 1u);
    return (unsigned short)(r >> 16);
}

union U8  { unsigned short us[8]; bf16x8 v; };
union H8  { _Float16 h[8]; f16x8 v; };
union PKW { bf16x2 h; unsigned int u; };
union PA4 { unsigned int u[4]; bf16x8 v; };

// register-pair lane swaps (gfx950): a[32:63] <-> b[0:31]  /  a[16:31]<->b[0:15], a[48:63]<->b[32:47]
static __device__ __forceinline__ void pl32swap(unsigned int& a, unsigned int& b) {
#if __has_builtin(__builtin_amdgcn_permlane32_swap)
    uint2v t = __builtin_amdgcn_permlane32_swap(a, b, false, false);
    a = t.x; b = t.y;
#else
    asm("s_nop 1\n\tv_permlane32_swap_b32 %0, %1" : "+v"(a), "+v"(b));
#endif
}
static __device__ __forceinline__ void pl16swap(unsigned int& a, unsigned int& b) {
#if __has_builtin(__builtin_amdgcn_permlane16_swap)
    uint2v t = __builtin_amdgcn_permlane16_swap(a, b, false, false);
    a = t.x; b = t.y;
#else
    asm("s_nop 1\n\tv_permlane16_swap_b32 %0, %1" : "+v"(a), "+v"(b));
#endif
}

// ---------------- prep: K -> fp16, V^T -> bf16 tiles; + sstart (merged) ----------------
// K region (ushort 0..4095):  16B slot = (c*2+hi)*64 + qd*16 + ln
//   holds K[row = hi*16+ln][d = c*32+qd*8 .. +7] as fp16.
// V region (ushort 4096..8191): 16B slot = sub*64 + sc*16 + dln
//   holds V^T[d = sub*16+dln][kv = sc*8 .. +7] as bf16.
// Blocks with blockIdx.x == T_/32 compute per-row segment-start indices.
__global__ __launch_bounds__(256)
void prep(const float* __restrict__ kg, const float* __restrict__ vg,
          const int* __restrict__ seg,
          unsigned short* __restrict__ ws, int* __restrict__ sstart)
{
    const int tid = threadIdx.x;
    const int x   = blockIdx.x;
    const int kvh = blockIdx.y;
    const int b   = blockIdx.z;

    if (x == T_ / 32) {
        // 16 blocks (8 kvh x 2 b) x 256 threads = 4096 rows
        int idx = (b * NKV_ + kvh) * 256 + tid;
        int bb = idx >> 11, t = idx & (T_ - 1);
        const int* sb = seg + bb * T_;
        int target = sb[t];
        int lo = 0, hi = t;
        while (lo < hi) { int mid = (lo + hi) >> 1; if (sb[mid] < target) lo = mid + 1; else hi = mid; }
        sstart[idx] = lo;
        return;
    }

    const int st = x;              // 32-col KV tile index
    unsigned short* base = ws + ((size_t)((b * NKV_ + kvh) * (T_ / 32) + st)) * TILE_US;

    // K: 512 tasks = 32 rows x 16 chunks(8 elems), fp16
    #pragma unroll
    for (int it = 0; it < 2; ++it) {
        int task = tid + it * 256;
        int r = task >> 4, c16 = task & 15;            // d = c16*8
        const float* kp = kg + (((size_t)(b * T_ + st * 32 + r)) * NKV_ + kvh) * D_ + c16 * 8;
        H8 hu;
        #pragma unroll
        for (int j = 0; j < 8; ++j) hu.h[j] = (_Float16)kp[j];
        int c = c16 >> 2, qd = c16 & 3, hi = r >> 4, ln = r & 15;
        int slot = (c * 2 + hi) * 64 + qd * 16 + ln;
        *(f16x8*)(base + slot * 8) = hu.v;
    }
    // V^T: 512 tasks = 128 d x 4 s-chunks(8 s), bf16
    #pragma unroll
    for (int it = 0; it < 2; ++it) {
        int task = tid + it * 256;
        int d = task & 127, sc = task >> 7;
        const float* vp = vg + (((size_t)(b * T_ + st * 32 + sc * 8)) * NKV_ + kvh) * D_ + d;
        U8 pk;
        #pragma unroll
        for (int j = 0; j < 8; ++j) pk.us[j] = f2bf(vp[j * (NKV_ * D_)]);
        int slot = (d >> 4) * 64 + sc * 16 + (d & 15);
        *(bf16x8*)(base + 4096 + slot * 8) = pk.v;
    }
}

// ---------------- main attention kernel (4 independent waves/block, 32 q-rows/wave) ----------------
__global__ __launch_bounds__(256)
void attn_fwd(const float* __restrict__ qg,
              const int* __restrict__ sstart,
              const unsigned short* __restrict__ ws,
              float* __restrict__ outg)
{
    const int tid  = threadIdx.x;
    const int wave = tid >> 6;
    const int lane = tid & 63;
    const int qd   = lane >> 4;
    const int ln   = lane & 15;

    const int kvh  = blockIdx.x;             // kv head; 4 waves = its 4 q-heads
    const int head = kvh * 4 + wave;
    const int chunk = (int)gridDim.y - 1 - (int)blockIdx.y;   // heavy-first
    const int b    = blockIdx.z;
    const int t0   = chunk * 32;

    const unsigned short* wsbase =
        ws + ((size_t)((b * NKV_ + kvh) * (T_ / 32))) * TILE_US + lane * 8;

    // load K(tile) and V(tile) fragments into named register buffers (16 KB/wave)
#define LOADKV(KB, VB, tl) do {                                                \
        const unsigned short* _tb = wsbase + (size_t)(tl) * TILE_US;           \
        _Pragma("unroll")                                                      \
        for (int _c = 0; _c < 4; ++_c) {                                       \
            KB[_c][0] = *(const f16x8*)(_tb + (_c * 2 + 0) * 512);             \
            KB[_c][1] = *(const f16x8*)(_tb + (_c * 2 + 1) * 512);             \
        }                                                                      \
        _Pragma("unroll")                                                      \
        for (int _s = 0; _s < 8; ++_s)                                         \
            VB[_s] = *(const bf16x8*)(_tb + 4096 + _s * 512);                  \
    } while (0)

    // One 16-row group: swapped QK -> mask -> exp2 -> in-reg transpose -> PV.
    // Lane(qd,ln): S[kv=_s0+qd*4+r (+16)][qrow=ln].
#define QKPV(QH, QL, OO, LL, RS_L, TROW_L, KB, VB, FAST) do {                  \
        f32x4 S0 = {0.f,0.f,0.f,0.f}, S1 = {0.f,0.f,0.f,0.f};                  \
        __builtin_amdgcn_s_setprio(1);                                         \
        _Pragma("unroll")                                                      \
        for (int c = 0; c < 4; ++c) {                                          \
            S0 = __builtin_amdgcn_mfma_f32_16x16x32_f16(KB[c][0], QH[c], S0,0,0,0); \
            S1 = __builtin_amdgcn_mfma_f32_16x16x32_f16(KB[c][1], QH[c], S1,0,0,0); \
            S0 = __builtin_amdgcn_mfma_f32_16x16x32_f16(KB[c][0], QL[c], S0,0,0,0); \
            S1 = __builtin_amdgcn_mfma_f32_16x16x32_f16(KB[c][1], QL[c], S1,0,0,0); \
        }                                                                      \
        __builtin_amdgcn_s_setprio(0);                                         \
        float p0[4], p1[4];                                                    \
        if (FAST) {                                                            \
            _Pragma("unroll")                                                  \
            for (int r = 0; r < 4; ++r) {                                      \
                p0[r] = exp2f(S0[r]);                                          \
                p1[r] = exp2f(S1[r]);                                          \
            }                                                                  \
        } else {                                                               \
            _Pragma("unroll")                                                  \
            for (int r = 0; r < 4; ++r) {                                      \
                int kv0 = _s0 + qd * 4 + r;                                    \
                int kv1 = kv0 + 16;                                            \
                float sv0 = (kv0 >= (RS_L) && kv0 <= (TROW_L)) ? S0[r] : MASKV;\
                float sv1 = (kv1 >= (RS_L) && kv1 <= (TROW_L)) ? S1[r] : MASKV;\
                p0[r] = exp2f(sv0);                                            \
                p1[r] = exp2f(sv1);                                            \
            }                                                                  \
        }                                                                      \
        LL += (p0[0] + p0[1]) + (p0[2] + p0[3])                                \
            + (p1[0] + p1[1]) + (p1[2] + p1[3]);                               \
        PKW c0, c1, c2, c3;                                                    \
        c0.h = (bf16x2){(__bf16)p0[0], (__bf16)p0[1]};                         \
        c1.h = (bf16x2){(__bf16)p0[2], (__bf16)p0[3]};                         \
        c2.h = (bf16x2){(__bf16)p1[0], (__bf16)p1[1]};                         \
        c3.h = (bf16x2){(__bf16)p1[2], (__bf16)p1[3]};                         \
        unsigned int w0 = c0.u, w1 = c1.u, w2 = c2.u, w3 = c3.u;               \
        pl32swap(w0, w2); pl32swap(w1, w3);                                    \
        pl16swap(w0, w2); pl16swap(w1, w3);                                    \
        PA4 pw; pw.u[0] = w0; pw.u[1] = w1; pw.u[2] = w2; pw.u[3] = w3;        \
        bf16x8 pa = pw.v;                                                      \
        __builtin_amdgcn_s_setprio(1);                                         \
        _Pragma("unroll")                                                      \
        for (int sub = 0; sub < 8; ++sub)                                      \
            OO[sub] = __builtin_amdgcn_mfma_f32_16x16x32_bf16(pa, VB[sub], OO[sub],0,0,0); \
        __builtin_amdgcn_s_setprio(0);                                         \
    } while (0)

    // Both 16-row groups against one K/V tile (loads amortized 2x)
#define COMPUTE(KB, VB, TL) do {                                               \
        const int _s0 = (TL) * 32;                                             \
        const bool fastall = (_s0 >= wave_rs_max) && (_s0 + 31 <= t0);         \
        QKPV(qh0, ql0, O0, l0, rs0_l, trow0_l, KB, VB, fastall);               \
        QKPV(qh1, ql1, O1, l1, rs1_l, trow1_l, KB, VB, fastall);               \
    } while (0)

    // ---- preload Q fragments for both 16-row groups, scaled by log2(e), fp16 hi/lo ----
    f16x8 qh0[4], ql0[4], qh1[4], ql1[4];
    #pragma unroll
    for (int g = 0; g < 2; ++g) {
        const float* qrow =
            qg + (((size_t)(b * T_ + (t0 + g * 16 + ln)) * NQ_) + head) * D_;
        #pragma unroll
        for (int c = 0; c < 4; ++c) {
            float4 a  = *(const float4*)(qrow + c * 32 + qd * 8);
            float4 b2 = *(const float4*)(qrow + c * 32 + qd * 8 + 4);
            float xs[8] = {a.x, a.y, a.z, a.w, b2.x, b2.y, b2.z, b2.w};
            H8 hu, lu;
            #pragma unroll
            for (int jj = 0; jj < 8; ++jj) {
                float x = xs[jj] * LOG2E;
                _Float16 h = (_Float16)x;
                hu.h[jj] = h;
                lu.h[jj] = (_Float16)(x - (float)h);
            }
            if (g == 0) { qh0[c] = hu.v; ql0[c] = lu.v; }
            else        { qh1[c] = hu.v; ql1[c] = lu.v; }
        }
    }

    // ---- per-lane row info for both groups ----
    const int trow0_l = t0 + ln;
    const int trow1_l = t0 + 16 + ln;
    const int rs0_l   = sstart[b * T_ + trow0_l];
    const int rs1_l   = sstart[b * T_ + trow1_l];
    const int wave_rs_max = sstart[b * T_ + t0 + 31];   // sorted -> max of 32 rows

    const int tile0   = sstart[b * T_ + t0] >> 5;       // wave-uniform (min row)
    const int n_tiles = chunk + 1;                      // causal: kv tiles 0..chunk

    f32x4 O0[8], O1[8];
    #pragma unroll
    for (int k = 0; k < 8; ++k) {
        O0[k] = (f32x4){0.f, 0.f, 0.f, 0.f};
        O1[k] = (f32x4){0.f, 0.f, 0.f, 0.f};
    }
    float l0 = 0.f, l1 = 0.f;

    f16x8  kA[4][2], kB_[4][2];
    bf16x8 vA[8], vB_[8];

    int t = tile0;
    LOADKV(kA, vA, t);                      // prologue
    while (t + 1 < n_tiles) {
        LOADKV(kB_, vB_, t + 1);            // prefetch under compute(A)
        COMPUTE(kA, vA, t);
        if (t + 2 < n_tiles) LOADKV(kA, vA, t + 2);
        COMPUTE(kB_, vB_, t + 1);
        t += 2;
    }
    if (t < n_tiles) COMPUTE(kA, vA, t);

    // ---- epilogue per group: reduce l across qd, redistribute, store ----
    #pragma unroll
    for (int g = 0; g < 2; ++g) {
        float l = (g == 0) ? l0 : l1;
        l += __shfl_xor(l, 16);
        l += __shfl_xor(l, 32);
        const float invl = 1.0f / l;        // per lane: denom for q-row = g*16+ln
        int trow[4];
        float inv[4];
        #pragma unroll
        for (int r = 0; r < 4; ++r) {
            trow[r] = t0 + g * 16 + qd * 4 + r;
            inv[r]  = __shfl(invl, qd * 4 + r);  // lane (qd*4+r) holds row's denom
        }
        #pragma unroll
        for (int sub = 0; sub < 8; ++sub) {
            #pragma unroll
            for (int r = 0; r < 4; ++r) {
                float ov = (g == 0) ? O0[sub][r] : O1[sub][r];
                outg[(((size_t)(b * T_ + trow[r]) * NQ_) + head) * D_ + sub * 16 + ln] =
                    ov * inv[r];
            }
        }
    }

#undef LOADKV
#undef QKPV
#undef COMPUTE
}

// ---------------- fallback (no-ws path) ----------------
#define KSTR 136
#define VSTR 40
#define PSTR 40
static __device__ __forceinline__ float bf2f(unsigned short h) {
    union { unsigned int u; float f; } c; c.u = (unsigned int)h << 16; return c.f;
}
__global__ __launch_bounds__(256)
void attn_fwd_fb(const float* __restrict__ qg,
                 const float* __restrict__ kg,
                 const float* __restrict__ vg,
                 const int* __restrict__ seg,
                 float* __restrict__ outg)
{
    __shared__ unsigned short sKh[32 * KSTR];
    __shared__ unsigned short sKl[32 * KSTR];
    __shared__ unsigned short sVt[128 * VSTR];
    __shared__ unsigned short sP[4][16 * PSTR];

    const int tid  = threadIdx.x;
    const int wave = tid >> 6;
    const int lane = tid & 63;
    const int qd   = lane >> 4;
    const int ln   = lane & 15;
    const int t0   = ((int)gridDim.x - 1 - (int)blockIdx.x) * 64;
    const int head = blockIdx.y;
    const int kvh  = head >> 2;
    const int b    = blockIdx.z;

    bf16x8 qh[4], ql[4];
    {
        const float* qrow =
            qg + (((size_t)(b * T_ + (t0 + wave * 16 + ln)) * NQ_) + head) * D_;
        #pragma unroll
        for (int c = 0; c < 4; ++c) {
            float4 a  = *(const float4*)(qrow + c * 32 + qd * 8);
            float4 b2 = *(const float4*)(qrow + c * 32 + qd * 8 + 4);
            float xs[8] = {a.x, a.y, a.z, a.w, b2.x, b2.y, b2.z, b2.w};
            U8 hu, lu;
            #pragma unroll
            for (int j = 0; j < 8; ++j) {
                unsigned short h = f2bf(xs[j]);
                hu.us[j] = h;
                lu.us[j] = f2bf(xs[j] - bf2f(h));
            }
            qh[c] = hu.v; ql[c] = lu.v;
        }
    }
    const int* sb = seg + (size_t)b * T_;
    int qseg[4];
    #pragma unroll
    for (int r = 0; r < 4; ++r) qseg[r] = sb[t0 + wave * 16 + qd * 4 + r];
    int tile0;
    {
        int target = sb[t0];
        int lo = 0, hi = t0;
        while (lo < hi) { int mid = (lo + hi) >> 1; if (sb[mid] < target) lo = mid + 1; else hi = mid; }
        tile0 = lo >> 5;
    }
    f32x4 O[8];
    #pragma unroll
    for (int i = 0; i < 8; ++i) O[i] = (f32x4){0.f, 0.f, 0.f, 0.f};
    float m_prev[4], l_lane[4];
    #pragma unroll
    for (int r = 0; r < 4; ++r) { m_prev[r] = MASKV; l_lane[r] = 0.f; }
    const int n_tiles = t0 / 32 + 2;

    for (int tile = tile0; tile < n_tiles; ++tile) {
        const int s0 = tile * 32;
        __syncthreads();
        #pragma unroll
        for (int it = 0; it < 2; ++it) {
            int task = tid + it * 256;
            int r = task >> 4, d = (task & 15) * 8;
            const float* kp = kg + (((size_t)(b * T_ + s0 + r) * NKV_) + kvh) * D_ + d;
            float4 a  = *(const float4*)(kp);
            float4 b2 = *(const float4*)(kp + 4);
            float xs[8] = {a.x, a.y, a.z, a.w, b2.x, b2.y, b2.z, b2.w};
            U8 hu, lu;
            #pragma unroll
            for (int j = 0; j < 8; ++j) {
                unsigned short h = f2bf(xs[j]);
                hu.us[j] = h;
                lu.us[j] = f2bf(xs[j] - bf2f(h));
            }
            *(bf16x8*)(sKh + r * KSTR + d) = hu.v;
            *(bf16x8*)(sKl + r * KSTR + d) = lu.v;
        }
        #pragma unroll
        for (int it = 0; it < 2; ++it) {
            int task = tid + it * 256;
            int d = task & 127, sg = task >> 7;
            const float* vp = vg + (((size_t)(b * T_ + s0 + sg * 8) * NKV_) + kvh) * D_ + d;
            U8 pk;
            #pragma unroll
            for (int j = 0; j < 8; ++j) pk.us[j] = f2bf(vp[j * (NKV_ * D_)]);
            *(bf16x8*)(sVt + d * VSTR + sg * 8) = pk.v;
        }
        __syncthreads();

        f32x4 S0 = {0.f,0.f,0.f,0.f}, S1 = {0.f,0.f,0.f,0.f};
        #pragma unroll
        for (int c = 0; c < 4; ++c) {
            bf16x8 kh0 = *(const bf16x8*)(sKh + ln * KSTR + c * 32 + qd * 8);
            bf16x8 kh1 = *(const bf16x8*)(sKh + (16 + ln) * KSTR + c * 32 + qd * 8);
            bf16x8 kl0 = *(const bf16x8*)(sKl + ln * KSTR + c * 32 + qd * 8);
            bf16x8 kl1 = *(const bf16x8*)(sKl + (16 + ln) * KSTR + c * 32 + qd * 8);
            S0 = __builtin_amdgcn_mfma_f32_16x16x32_bf16(qh[c], kh0, S0, 0, 0, 0);
            S1 = __builtin_amdgcn_mfma_f32_16x16x32_bf16(qh[c], kh1, S1, 0, 0, 0);
            S0 = __builtin_amdgcn_mfma_f32_16x16x32_bf16(qh[c], kl0, S0, 0, 0, 0);
            S1 = __builtin_amdgcn_mfma_f32_16x16x32_bf16(qh[c], kl1, S1, 0, 0, 0);
            S0 = __builtin_amdgcn_mfma_f32_16x16x32_bf16(ql[c], kh0, S0, 0, 0, 0);
            S1 = __builtin_amdgcn_mfma_f32_16x16x32_bf16(ql[c], kh1, S1, 0, 0, 0);
        }
        const int ks0 = sb[s0 + ln];
        const int ks1 = sb[s0 + 16 + ln];
        float p0[4], p1[4], alpha[4];
        #pragma unroll
        for (int r = 0; r < 4; ++r) {
            const int trow = t0 + wave * 16 + qd * 4 + r;
            float s0v = ((s0 + ln <= trow) && (ks0 == qseg[r])) ? S0[r] : MASKV;
            float s1v = ((s0 + 16 + ln <= trow) && (ks1 == qseg[r])) ? S1[r] : MASKV;
            float mx = fmaxf(s0v, s1v);
            mx = fmaxf(mx, __shfl_xor(mx, 1));
            mx = fmaxf(mx, __shfl_xor(mx, 2));
            mx = fmaxf(mx, __shfl_xor(mx, 4));
            mx = fmaxf(mx, __shfl_xor(mx, 8));
            const float mn = fmaxf(m_prev[r], mx);
            alpha[r] = __expf(m_prev[r] - mn);
            p0[r] = __expf(s0v - mn);
            p1[r] = __expf(s1v - mn);
            l_lane[r] = alpha[r] * l_lane[r] + p0[r] + p1[r];
            m_prev[r] = mn;
        }
        #pragma unroll
        for (int i = 0; i < 8; ++i) {
            O[i][0] *= alpha[0]; O[i][1] *= alpha[1];
            O[i][2] *= alpha[2]; O[i][3] *= alpha[3];
        }
        {
            unsigned short* pw = sP[wave] + (qd * 4) * PSTR + ln;
            #pragma unroll
            for (int r = 0; r < 4; ++r) {
                pw[r * PSTR]      = f2bf(p0[r]);
                pw[r * PSTR + 16] = f2bf(p1[r]);
            }
        }
        asm volatile("s_waitcnt lgkmcnt(0)" ::: "memory");
        bf16x8 pa = *(const bf16x8*)(sP[wave] + ln * PSTR + qd * 8);
        #pragma unroll
        for (int sub = 0; sub < 8; ++sub) {
            bf16x8 bv = *(const bf16x8*)(sVt + (sub * 16 + ln) * VSTR + qd * 8);
            O[sub] = __builtin_amdgcn_mfma_f32_16x16x32_bf16(pa, bv, O[sub], 0, 0, 0);
        }
    }
    float inv[4];
    #pragma unroll
    for (int r = 0; r < 4; ++r) {
        float l = l_lane[r];
        l += __shfl_xor(l, 1);
        l += __shfl_xor(l, 2);
        l += __shfl_xor(l, 4);
        l += __shfl_xor(l, 8);
        inv[r] = 1.0f / l;
    }
    #pragma unroll
    for (int sub = 0; sub < 8; ++sub) {
        #pragma unroll
        for (int r = 0; r < 4; ++r) {
            const int trow = t0 + wave * 16 + qd * 4 + r;
            outg[(((size_t)(b * T_ + trow) * NQ_) + head) * D_ + sub * 16 + ln] =
                O[sub][r] * inv[r];
        }
    }
}

extern "C" void kernel_launch(void* const* d_in, const int* in_sizes, int n_in,
                              void* d_out, int out_size, void* d_ws, size_t ws_size,
                              hipStream_t stream) {
    const float* q  = (const float*)d_in[0];
    const float* k  = (const float*)d_in[1];
    const float* v  = (const float*)d_in[2];
    const int*   sg = (const int*)d_in[3];
    float*       o  = (float*)d_out;
    if (ws_size >= WS_NEED) {
        unsigned short* ws = (unsigned short*)d_ws;
        int* sstart = (int*)((char*)d_ws + WS_TILES_BYTES);
        prep<<<dim3(T_ / 32 + 1, NKV_, B_), dim3(256), 0, stream>>>(k, v, sg, ws, sstart);
        attn_fwd<<<dim3(NKV_, T_ / 32, B_), dim3(256), 0, stream>>>(q, sstart, ws, o);
    } else {
        attn_fwd_fb<<<dim3(T_ / 64, NQ_, B_), dim3(256), 0, stream>>>(q, k, v, sg, o);
    }
}

// Round 9
// 186.319 us; speedup vs baseline: 1.1043x; 1.0249x over previous
//
#include <hip/hip_runtime.h>

// GQA causal+segment-masked flash attention. fp32 in/out.
// B=2, T=2048, NQ=32 (8 kv heads x 4), D=128.
// R16: 16-KV half-tiles so the register DOUBLE BUFFER actually fits.
// R11/R14/R15 all showed the compiler collapsing the 32-kv dbuf (need
// ~300 VGPR, binary showed 128-168) and sinking loads to use -> every
// tile exposed ~500cyc load latency serially (the ~1000cyc/tile
// invariant). With 16-kv tiles: Q64+O64+2x32 KV+temps ~= 225 VGPR < 256.
// Bonus: swapped-QK S[kv=qd*4+r][qrow=ln] is ALREADY the 16x16x16 PV
// A-fragment layout -> permlane transpose deleted (2 cvt_pk only).
// V re-packed in prep so each PV B-fragment pair is one 16B load.
// Grid/waves as R15: (8 kvh, 64 chunks, 2) x 4 independent waves
// (one per q-head, shared KV stream), heavy-first, no LDS, no barriers.

typedef __bf16 bf16x8 __attribute__((ext_vector_type(8)));
typedef __bf16 bf16x2 __attribute__((ext_vector_type(2)));
typedef _Float16 f16x8 __attribute__((ext_vector_type(8)));
typedef float f32x4 __attribute__((ext_vector_type(4)));
typedef short s16x4 __attribute__((ext_vector_type(4)));
typedef unsigned int u32x4 __attribute__((ext_vector_type(4)));
typedef unsigned int uint2v __attribute__((ext_vector_type(2)));

#define B_   2
#define T_   2048
#define NQ_  32
#define NKV_ 8
#define D_   128

#define MASKV (-3.0e38f)
#define LOG2E 1.44269504f
#define TILE16_US 4096         // ushorts per 16-col KV tile: 4KB fp16 K + 4KB bf16 V-frag
#define WS_TILES_BYTES ((size_t)B_ * NKV_ * (T_ / 16) * TILE16_US * 2)   // 16777216
#define WS_NEED (WS_TILES_BYTES + (size_t)B_ * T_ * 4)

static __device__ __forceinline__ unsigned short f2bf(float x) {
    union { float f; unsigned int u; } c; c.f = x;
    unsigned int r = c.u + 0x7fffu + ((c.u >> 16) & 1u);
    return (unsigned short)(r >> 16);
}

union U8  { unsigned short us[8]; bf16x8 v; };
union H8  { _Float16 h[8]; f16x8 v; };
union PKW { bf16x2 h; unsigned int u; };
union W2S { unsigned int u[2]; s16x4 s; };

static __device__ __forceinline__ f32x4 mfma_pv(s16x4 a, s16x4 b, f32x4 c) {
#if __has_builtin(__builtin_amdgcn_mfma_f32_16x16x16bf16_1k)
    return __builtin_amdgcn_mfma_f32_16x16x16bf16_1k(a, b, c, 0, 0, 0);
#else
    asm volatile("v_mfma_f32_16x16x16_bf16 %0, %1, %2, %0"
                 : "+v"(c) : "v"(a), "v"(b));
    return c;
#endif
}

// ---------------- prep: K -> fp16, V -> bf16 PV-fragments; + sstart (merged) ----------------
// Per 16-kv tile tg (ushorts, TILE16_US=4096):
//  K region [0..2047]:  16B slot (c*64+l): K[kv=tg*16+ln][d=c*32+qd*8 .. +7] fp16
//    -> QK A-fragment: lane l reads 16B at c*512 + l*8.
//  V region [2048..4095]: 16B slot (sp*64+l):
//    bytes 0..7 : V[kv=tg*16+qd*4+j][d=(2sp)*16+ln]   j=0..3 (bf16)  = PV B-frag sub=2sp
//    bytes 8..15: V[kv=tg*16+qd*4+j][d=(2sp+1)*16+ln] j=0..3 (bf16)  = PV B-frag sub=2sp+1
// Blocks with blockIdx.x == T_/32 compute per-row segment-start indices.
__global__ __launch_bounds__(256)
void prep(const float* __restrict__ kg, const float* __restrict__ vg,
          const int* __restrict__ seg,
          unsigned short* __restrict__ ws, int* __restrict__ sstart)
{
    const int tid = threadIdx.x;
    const int x   = blockIdx.x;
    const int kvh = blockIdx.y;
    const int b   = blockIdx.z;

    if (x == T_ / 32) {
        int idx = (b * NKV_ + kvh) * 256 + tid;   // 16 blocks x 256 = 4096 rows
        int bb = idx >> 11, t = idx & (T_ - 1);
        const int* sb = seg + bb * T_;
        int target = sb[t];
        int lo = 0, hi = t;
        while (lo < hi) { int mid = (lo + hi) >> 1; if (sb[mid] < target) lo = mid + 1; else hi = mid; }
        sstart[idx] = lo;
        return;
    }

    // this block handles 32 kv rows = 16-kv tiles (2x, 2x+1)
    unsigned short* base0 =
        ws + ((size_t)((b * NKV_ + kvh) * (T_ / 16) + 2 * x)) * TILE16_US;

    // K: 512 tasks = 2 tiles x 4 c x 64 lanes
    #pragma unroll
    for (int it = 0; it < 2; ++it) {
        int task = tid + it * 256;
        int tu = task >> 8, rem = task & 255;
        int c = rem >> 6, l = rem & 63;
        int qd = l >> 4, ln = l & 15;
        int kvrow = x * 32 + tu * 16 + ln;
        const float* kp = kg + (((size_t)(b * T_ + kvrow)) * NKV_ + kvh) * D_ + c * 32 + qd * 8;
        H8 hu;
        #pragma unroll
        for (int j = 0; j < 8; ++j) hu.h[j] = (_Float16)kp[j];
        *(f16x8*)(base0 + tu * TILE16_US + (c * 64 + l) * 8) = hu.v;
    }
    // V: 512 tasks = 2 tiles x 4 sp x 64 lanes
    #pragma unroll
    for (int it = 0; it < 2; ++it) {
        int task = tid + it * 256;
        int tu = task >> 8, rem = task & 255;
        int sp = rem >> 6, l = rem & 63;
        int qd = l >> 4, ln = l & 15;
        U8 pk;
        #pragma unroll
        for (int j = 0; j < 4; ++j) {
            int kv = x * 32 + tu * 16 + qd * 4 + j;
            const float* vp = vg + (((size_t)(b * T_ + kv)) * NKV_ + kvh) * D_;
            pk.us[j]     = f2bf(vp[(2 * sp) * 16 + ln]);
            pk.us[4 + j] = f2bf(vp[(2 * sp + 1) * 16 + ln]);
        }
        *(bf16x8*)(base0 + tu * TILE16_US + 2048 + (sp * 64 + l) * 8) = pk.v;
    }
}

// ---------------- main attention kernel (4 independent waves/block, 32 q-rows/wave) ----------------
__global__ __launch_bounds__(256)
void attn_fwd(const float* __restrict__ qg,
              const int* __restrict__ sstart,
              const unsigned short* __restrict__ ws,
              float* __restrict__ outg)
{
    const int tid  = threadIdx.x;
    const int wave = tid >> 6;
    const int lane = tid & 63;
    const int qd   = lane >> 4;
    const int ln   = lane & 15;

    const int kvh  = blockIdx.x;             // kv head; 4 waves = its 4 q-heads
    const int head = kvh * 4 + wave;
    const int chunk = (int)gridDim.y - 1 - (int)blockIdx.y;   // heavy-first
    const int b    = blockIdx.z;
    const int t0   = chunk * 32;

    const unsigned short* wsbase =
        ws + ((size_t)((b * NKV_ + kvh) * (T_ / 16))) * TILE16_US + lane * 8;

    // 16-kv tile fragments: K 4x f16x8 (16 VGPR), V 4x u32x4 (16 VGPR)
#define LOADKV(KB, VB, tg) do {                                                \
        const unsigned short* _tb = wsbase + (size_t)(tg) * TILE16_US;         \
        _Pragma("unroll")                                                      \
        for (int _c = 0; _c < 4; ++_c)                                         \
            KB[_c] = *(const f16x8*)(_tb + _c * 512);                          \
        _Pragma("unroll")                                                      \
        for (int _s = 0; _s < 4; ++_s)                                         \
            VB[_s] = *(const u32x4*)(_tb + 2048 + _s * 512);                   \
    } while (0)

    // One 16-row group vs one 16-kv tile. Lane(qd,ln): S[r]=S[kv=_s0+qd*4+r][qrow=ln].
    // pa (= P row ln, k=qd*4+i) is exactly the 16x16x16 A layout -> no cross-lane ops.
#define QKPV(QH, QL, OO, LL, RS_L, TROW_L, KB, VB, FAST) do {                  \
        f32x4 S = {0.f, 0.f, 0.f, 0.f};                                        \
        __builtin_amdgcn_s_setprio(1);                                         \
        _Pragma("unroll")                                                      \
        for (int c = 0; c < 4; ++c) {                                          \
            S = __builtin_amdgcn_mfma_f32_16x16x32_f16(KB[c], QH[c], S,0,0,0); \
            S = __builtin_amdgcn_mfma_f32_16x16x32_f16(KB[c], QL[c], S,0,0,0); \
        }                                                                      \
        __builtin_amdgcn_s_setprio(0);                                         \
        float p[4];                                                            \
        if (FAST) {                                                            \
            _Pragma("unroll")                                                  \
            for (int r = 0; r < 4; ++r) p[r] = exp2f(S[r]);                    \
        } else {                                                               \
            _Pragma("unroll")                                                  \
            for (int r = 0; r < 4; ++r) {                                      \
                int kv = _s0 + qd * 4 + r;                                     \
                float sv = (kv >= (RS_L) && kv <= (TROW_L)) ? S[r] : MASKV;    \
                p[r] = exp2f(sv);                                              \
            }                                                                  \
        }                                                                      \
        LL += (p[0] + p[1]) + (p[2] + p[3]);                                   \
        PKW w0, w1;                                                            \
        w0.h = (bf16x2){(__bf16)p[0], (__bf16)p[1]};                           \
        w1.h = (bf16x2){(__bf16)p[2], (__bf16)p[3]};                           \
        W2S pa; pa.u[0] = w0.u; pa.u[1] = w1.u;                                \
        __builtin_amdgcn_s_setprio(1);                                         \
        _Pragma("unroll")                                                      \
        for (int sp = 0; sp < 4; ++sp) {                                       \
            W2S vlo, vhi;                                                      \
            vlo.u[0] = VB[sp][0]; vlo.u[1] = VB[sp][1];                        \
            vhi.u[0] = VB[sp][2]; vhi.u[1] = VB[sp][3];                        \
            OO[2 * sp]     = mfma_pv(pa.s, vlo.s, OO[2 * sp]);                 \
            OO[2 * sp + 1] = mfma_pv(pa.s, vhi.s, OO[2 * sp + 1]);             \
        }                                                                      \
        __builtin_amdgcn_s_setprio(0);                                         \
    } while (0)

    // Both 16-row groups against one 16-kv tile (loads amortized 2x)
#define COMPUTE(KB, VB, TG) do {                                               \
        const int _s0 = (TG) * 16;                                             \
        const bool fastall = (_s0 >= wave_rs_max) && (_s0 + 15 <= t0);         \
        QKPV(qh0, ql0, O0, l0, rs0_l, trow0_l, KB, VB, fastall);               \
        QKPV(qh1, ql1, O1, l1, rs1_l, trow1_l, KB, VB, fastall);               \
    } while (0)

    // ---- preload Q fragments for both 16-row groups, scaled by log2(e), fp16 hi/lo ----
    f16x8 qh0[4], ql0[4], qh1[4], ql1[4];
    #pragma unroll
    for (int g = 0; g < 2; ++g) {
        const float* qrow =
            qg + (((size_t)(b * T_ + (t0 + g * 16 + ln)) * NQ_) + head) * D_;
        #pragma unroll
        for (int c = 0; c < 4; ++c) {
            float4 a  = *(const float4*)(qrow + c * 32 + qd * 8);
            float4 b2 = *(const float4*)(qrow + c * 32 + qd * 8 + 4);
            float xs[8] = {a.x, a.y, a.z, a.w, b2.x, b2.y, b2.z, b2.w};
            H8 hu, lu;
            #pragma unroll
            for (int jj = 0; jj < 8; ++jj) {
                float x = xs[jj] * LOG2E;
                _Float16 h = (_Float16)x;
                hu.h[jj] = h;
                lu.h[jj] = (_Float16)(x - (float)h);
            }
            if (g == 0) { qh0[c] = hu.v; ql0[c] = lu.v; }
            else        { qh1[c] = hu.v; ql1[c] = lu.v; }
        }
    }

    // ---- per-lane row info for both groups (this lane's q-rows are ln / 16+ln) ----
    const int trow0_l = t0 + ln;
    const int trow1_l = t0 + 16 + ln;
    const int rs0_l   = sstart[b * T_ + trow0_l];
    const int rs1_l   = sstart[b * T_ + trow1_l];
    const int wave_rs_max = sstart[b * T_ + t0 + 31];   // sorted -> max of 32 rows

    const int tile0   = sstart[b * T_ + t0] >> 4;       // wave-uniform (min row)
    const int n_tiles = 2 * chunk + 2;                  // causal: 16-kv tiles 0..2c+1

    f32x4 O0[8], O1[8];
    #pragma unroll
    for (int k = 0; k < 8; ++k) {
        O0[k] = (f32x4){0.f, 0.f, 0.f, 0.f};
        O1[k] = (f32x4){0.f, 0.f, 0.f, 0.f};
    }
    float l0 = 0.f, l1 = 0.f;

    f16x8 kA[4], kB_[4];
    u32x4 vA[4], vB_[4];

    int t = tile0;
    LOADKV(kA, vA, t);                      // prologue
    while (t + 1 < n_tiles) {
        LOADKV(kB_, vB_, t + 1);            // prefetch under compute(A)
        COMPUTE(kA, vA, t);
        if (t + 2 < n_tiles) LOADKV(kA, vA, t + 2);
        COMPUTE(kB_, vB_, t + 1);
        t += 2;
    }
    if (t < n_tiles) COMPUTE(kA, vA, t);

    // ---- epilogue per group: reduce l across qd, redistribute, store ----
    #pragma unroll
    for (int g = 0; g < 2; ++g) {
        float l = (g == 0) ? l0 : l1;
        l += __shfl_xor(l, 16);
        l += __shfl_xor(l, 32);
        const float invl = 1.0f / l;        // per lane: denom for q-row = g*16+ln
        int trow[4];
        float inv[4];
        #pragma unroll
        for (int r = 0; r < 4; ++r) {
            trow[r] = t0 + g * 16 + qd * 4 + r;
            inv[r]  = __shfl(invl, qd * 4 + r);  // lane (qd*4+r) holds row's denom
        }
        #pragma unroll
        for (int sub = 0; sub < 8; ++sub) {
            #pragma unroll
            for (int r = 0; r < 4; ++r) {
                float ov = (g == 0) ? O0[sub][r] : O1[sub][r];
                outg[(((size_t)(b * T_ + trow[r]) * NQ_) + head) * D_ + sub * 16 + ln] =
                    ov * inv[r];
            }
        }
    }

#undef LOADKV
#undef QKPV
#undef COMPUTE
}

// ---------------- fallback (no-ws path) ----------------
#define KSTR 136
#define VSTR 40
#define PSTR 40
static __device__ __forceinline__ float bf2f(unsigned short h) {
    union { unsigned int u; float f; } c; c.u = (unsigned int)h << 16; return c.f;
}
__global__ __launch_bounds__(256)
void attn_fwd_fb(const float* __restrict__ qg,
                 const float* __restrict__ kg,
                 const float* __restrict__ vg,
                 const int* __restrict__ seg,
                 float* __restrict__ outg)
{
    __shared__ unsigned short sKh[32 * KSTR];
    __shared__ unsigned short sKl[32 * KSTR];
    __shared__ unsigned short sVt[128 * VSTR];
    __shared__ unsigned short sP[4][16 * PSTR];

    const int tid  = threadIdx.x;
    const int wave = tid >> 6;
    const int lane = tid & 63;
    const int qd   = lane >> 4;
    const int ln   = lane & 15;
    const int t0   = ((int)gridDim.x - 1 - (int)blockIdx.x) * 64;
    const int head = blockIdx.y;
    const int kvh  = head >> 2;
    const int b    = blockIdx.z;

    bf16x8 qh[4], ql[4];
    {
        const float* qrow =
            qg + (((size_t)(b * T_ + (t0 + wave * 16 + ln)) * NQ_) + head) * D_;
        #pragma unroll
        for (int c = 0; c < 4; ++c) {
            float4 a  = *(const float4*)(qrow + c * 32 + qd * 8);
            float4 b2 = *(const float4*)(qrow + c * 32 + qd * 8 + 4);
            float xs[8] = {a.x, a.y, a.z, a.w, b2.x, b2.y, b2.z, b2.w};
            U8 hu, lu;
            #pragma unroll
            for (int j = 0; j < 8; ++j) {
                unsigned short h = f2bf(xs[j]);
                hu.us[j] = h;
                lu.us[j] = f2bf(xs[j] - bf2f(h));
            }
            qh[c] = hu.v; ql[c] = lu.v;
        }
    }
    const int* sb = seg + (size_t)b * T_;
    int qseg[4];
    #pragma unroll
    for (int r = 0; r < 4; ++r) qseg[r] = sb[t0 + wave * 16 + qd * 4 + r];
    int tile0;
    {
        int target = sb[t0];
        int lo = 0, hi = t0;
        while (lo < hi) { int mid = (lo + hi) >> 1; if (sb[mid] < target) lo = mid + 1; else hi = mid; }
        tile0 = lo >> 5;
    }
    f32x4 O[8];
    #pragma unroll
    for (int i = 0; i < 8; ++i) O[i] = (f32x4){0.f, 0.f, 0.f, 0.f};
    float m_prev[4], l_lane[4];
    #pragma unroll
    for (int r = 0; r < 4; ++r) { m_prev[r] = MASKV; l_lane[r] = 0.f; }
    const int n_tiles = t0 / 32 + 2;

    for (int tile = tile0; tile < n_tiles; ++tile) {
        const int s0 = tile * 32;
        __syncthreads();
        #pragma unroll
        for (int it = 0; it < 2; ++it) {
            int task = tid + it * 256;
            int r = task >> 4, d = (task & 15) * 8;
            const float* kp = kg + (((size_t)(b * T_ + s0 + r) * NKV_) + kvh) * D_ + d;
            float4 a  = *(const float4*)(kp);
            float4 b2 = *(const float4*)(kp + 4);
            float xs[8] = {a.x, a.y, a.z, a.w, b2.x, b2.y, b2.z, b2.w};
            U8 hu, lu;
            #pragma unroll
            for (int j = 0; j < 8; ++j) {
                unsigned short h = f2bf(xs[j]);
                hu.us[j] = h;
                lu.us[j] = f2bf(xs[j] - bf2f(h));
            }
            *(bf16x8*)(sKh + r * KSTR + d) = hu.v;
            *(bf16x8*)(sKl + r * KSTR + d) = lu.v;
        }
        #pragma unroll
        for (int it = 0; it < 2; ++it) {
            int task = tid + it * 256;
            int d = task & 127, sg = task >> 7;
            const float* vp = vg + (((size_t)(b * T_ + s0 + sg * 8) * NKV_) + kvh) * D_ + d;
            U8 pk;
            #pragma unroll
            for (int j = 0; j < 8; ++j) pk.us[j] = f2bf(vp[j * (NKV_ * D_)]);
            *(bf16x8*)(sVt + d * VSTR + sg * 8) = pk.v;
        }
        __syncthreads();

        f32x4 S0 = {0.f,0.f,0.f,0.f}, S1 = {0.f,0.f,0.f,0.f};
        #pragma unroll
        for (int c = 0; c < 4; ++c) {
            bf16x8 kh0 = *(const bf16x8*)(sKh + ln * KSTR + c * 32 + qd * 8);
            bf16x8 kh1 = *(const bf16x8*)(sKh + (16 + ln) * KSTR + c * 32 + qd * 8);
            bf16x8 kl0 = *(const bf16x8*)(sKl + ln * KSTR + c * 32 + qd * 8);
            bf16x8 kl1 = *(const bf16x8*)(sKl + (16 + ln) * KSTR + c * 32 + qd * 8);
            S0 = __builtin_amdgcn_mfma_f32_16x16x32_bf16(qh[c], kh0, S0, 0, 0, 0);
            S1 = __builtin_amdgcn_mfma_f32_16x16x32_bf16(qh[c], kh1, S1, 0, 0, 0);
            S0 = __builtin_amdgcn_mfma_f32_16x16x32_bf16(qh[c], kl0, S0, 0, 0, 0);
            S1 = __builtin_amdgcn_mfma_f32_16x16x32_bf16(qh[c], kl1, S1, 0, 0, 0);
            S0 = __builtin_amdgcn_mfma_f32_16x16x32_bf16(ql[c], kh0, S0, 0, 0, 0);
            S1 = __builtin_amdgcn_mfma_f32_16x16x32_bf16(ql[c], kh1, S1, 0, 0, 0);
        }
        const int ks0 = sb[s0 + ln];
        const int ks1 = sb[s0 + 16 + ln];
        float p0[4], p1[4], alpha[4];
        #pragma unroll
        for (int r = 0; r < 4; ++r) {
            const int trow = t0 + wave * 16 + qd * 4 + r;
            float s0v = ((s0 + ln <= trow) && (ks0 == qseg[r])) ? S0[r] : MASKV;
            float s1v = ((s0 + 16 + ln <= trow) && (ks1 == qseg[r])) ? S1[r] : MASKV;
            float mx = fmaxf(s0v, s1v);
            mx = fmaxf(mx, __shfl_xor(mx, 1));
            mx = fmaxf(mx, __shfl_xor(mx, 2));
            mx = fmaxf(mx, __shfl_xor(mx, 4));
            mx = fmaxf(mx, __shfl_xor(mx, 8));
            const float mn = fmaxf(m_prev[r], mx);
            alpha[r] = __expf(m_prev[r] - mn);
            p0[r] = __expf(s0v - mn);
            p1[r] = __expf(s1v - mn);
            l_lane[r] = alpha[r] * l_lane[r] + p0[r] + p1[r];
            m_prev[r] = mn;
        }
        #pragma unroll
        for (int i = 0; i < 8; ++i) {
            O[i][0] *= alpha[0]; O[i][1] *= alpha[1];
            O[i][2] *= alpha[2]; O[i][3] *= alpha[3];
        }
        {
            unsigned short* pw = sP[wave] + (qd * 4) * PSTR + ln;
            #pragma unroll
            for (int r = 0; r < 4; ++r) {
                pw[r * PSTR]      = f2bf(p0[r]);
                pw[r * PSTR + 16] = f2bf(p1[r]);
            }
        }
        asm volatile("s_waitcnt lgkmcnt(0)" ::: "memory");
        bf16x8 pa = *(const bf16x8*)(sP[wave] + ln * PSTR + qd * 8);
        #pragma unroll
        for (int sub = 0; sub < 8; ++sub) {
            bf16x8 bv = *(const bf16x8*)(sVt + (sub * 16 + ln) * VSTR + qd * 8);
            O[sub] = __builtin_amdgcn_mfma_f32_16x16x32_bf16(pa, bv, O[sub], 0, 0, 0);
        }
    }
    float inv[4];
    #pragma unroll
    for (int r = 0; r < 4; ++r) {
        float l = l_lane[r];
        l += __shfl_xor(l, 1);
        l += __shfl_xor(l, 2);
        l += __shfl_xor(l, 4);
        l += __shfl_xor(l, 8);
        inv[r] = 1.0f / l;
    }
    #pragma unroll
    for (int sub = 0; sub < 8; ++sub) {
        #pragma unroll
        for (int r = 0; r < 4; ++r) {
            const int trow = t0 + wave * 16 + qd * 4 + r;
            outg[(((size_t)(b * T_ + trow) * NQ_) + head) * D_ + sub * 16 + ln] =
                O[sub][r] * inv[r];
        }
    }
}

extern "C" void kernel_launch(void* const* d_in, const int* in_sizes, int n_in,
                              void* d_out, int out_size, void* d_ws, size_t ws_size,
                              hipStream_t stream) {
    const float* q  = (const float*)d_in[0];
    const float* k  = (const float*)d_in[1];
    const float* v  = (const float*)d_in[2];
    const int*   sg = (const int*)d_in[3];
    float*       o  = (float*)d_out;
    if (ws_size >= WS_NEED) {
        unsigned short* ws = (unsigned short*)d_ws;
        int* sstart = (int*)((char*)d_ws + WS_TILES_BYTES);
        prep<<<dim3(T_ / 32 + 1, NKV_, B_), dim3(256), 0, stream>>>(k, v, sg, ws, sstart);
        attn_fwd<<<dim3(NKV_, T_ / 32, B_), dim3(256), 0, stream>>>(q, sstart, ws, o);
    } else {
        attn_fwd_fb<<<dim3(T_ / 64, NQ_, B_), dim3(256), 0, stream>>>(q, k, v, sg, o);
    }
}

// Round 10
// 183.243 us; speedup vs baseline: 1.1228x; 1.0168x over previous
//
#include <hip/hip_runtime.h>

// GQA causal+segment-masked flash attention. fp32 in/out.
// B=2, T=2048, NQ=32 (8 kv heads x 4), D=128.
// R17: minimal-MFMA structure. R16 recalibration: MfmaUtil is an
// issue-slot proxy (x4.85 = real busy ~90%) -> we are MFMA-issue-bound.
// R16's K=16 PV cost +33% MFMA count. This round: R15's minimal count
// (48 MFMA per 32-kv: QK hi/lo fp16 16x16x32 + PV K=32) in R16's
// schedulable form: 16-kv K-chunks (16-VGPR bufs, true dbuf), P stashed
// per half as packed bf16, R8-verified permlane recipe recombines at a
// per-pair PV. Straight-line loop (even pair count via tile0&~1, extra
// half-tile masked to p=0; branchless always-masked exp2), and
// sched_barrier(0) after each prefetch clump so loads can't be sunk.
// Grid as R15/R16: (8 kvh, 64 chunks, 2) x 4 independent waves.

typedef __bf16 bf16x8 __attribute__((ext_vector_type(8)));
typedef __bf16 bf16x2 __attribute__((ext_vector_type(2)));
typedef _Float16 f16x8 __attribute__((ext_vector_type(8)));
typedef float f32x4 __attribute__((ext_vector_type(4)));
typedef unsigned int uint2v __attribute__((ext_vector_type(2)));

#define B_   2
#define T_   2048
#define NQ_  32
#define NKV_ 8
#define D_   128

#define MASKV (-3.0e38f)
#define LOG2E 1.44269504f
#define PAIR_US 8192   // ushorts per 32-kv pair: 4KB K(lo) + 4KB K(hi) + 8KB V-frags
#define WS_TILES_BYTES ((size_t)B_ * NKV_ * (T_ / 32) * PAIR_US * 2)   // 16777216
#define WS_NEED (WS_TILES_BYTES + (size_t)B_ * T_ * 4)

static __device__ __forceinline__ unsigned short f2bf(float x) {
    union { float f; unsigned int u; } c; c.f = x;
    unsigned int r = c.u + 0x7fffu + ((c.u >> 16) & 1u);
    return (unsigned short)(r >> 16);
}

union U8  { unsigned short us[8]; bf16x8 v; };
union H8  { _Float16 h[8]; f16x8 v; };
union PKW { bf16x2 h; unsigned int u; };
union PA4 { unsigned int u[4]; bf16x8 v; };

// register-pair lane swaps (gfx950): a[32:63] <-> b[0:31]  /  a[16:31]<->b[0:15], a[48:63]<->b[32:47]
static __device__ __forceinline__ void pl32swap(unsigned int& a, unsigned int& b) {
#if __has_builtin(__builtin_amdgcn_permlane32_swap)
    uint2v t = __builtin_amdgcn_permlane32_swap(a, b, false, false);
    a = t.x; b = t.y;
#else
    asm("s_nop 1\n\tv_permlane32_swap_b32 %0, %1" : "+v"(a), "+v"(b));
#endif
}
static __device__ __forceinline__ void pl16swap(unsigned int& a, unsigned int& b) {
#if __has_builtin(__builtin_amdgcn_permlane16_swap)
    uint2v t = __builtin_amdgcn_permlane16_swap(a, b, false, false);
    a = t.x; b = t.y;
#else
    asm("s_nop 1\n\tv_permlane16_swap_b32 %0, %1" : "+v"(a), "+v"(b));
#endif
}

// ---------------- prep: per 32-kv pair {K lo-half, K hi-half, V K=32 frags}; + sstart ----------------
// Pair p region (PAIR_US=8192 ushorts):
//  [tu*2048 .. +2047], tu=0,1: K 16-kv tile 2p+tu. 16B slot (c*64+l):
//      K[kv=(2p+tu)*16+ln(l)][d=c*32+qd(l)*8 .. +7] as fp16  (QK A-frag, lane l)
//  [4096 .. 8191]: V frags. 16B slot (sub*64+l):
//      V[kv=32p+qd(l)*8+j][d=sub*16+ln(l)], j=0..7, bf16   (PV K=32 B-frag)
// Blocks with blockIdx.x == T_/32 compute per-row segment-start indices.
__global__ __launch_bounds__(256)
void prep(const float* __restrict__ kg, const float* __restrict__ vg,
          const int* __restrict__ seg,
          unsigned short* __restrict__ ws, int* __restrict__ sstart)
{
    const int tid = threadIdx.x;
    const int x   = blockIdx.x;
    const int kvh = blockIdx.y;
    const int b   = blockIdx.z;

    if (x == T_ / 32) {
        int idx = (b * NKV_ + kvh) * 256 + tid;   // 16 blocks x 256 = 4096 rows
        int bb = idx >> 11, t = idx & (T_ - 1);
        const int* sb = seg + bb * T_;
        int target = sb[t];
        int lo = 0, hi = t;
        while (lo < hi) { int mid = (lo + hi) >> 1; if (sb[mid] < target) lo = mid + 1; else hi = mid; }
        sstart[idx] = lo;
        return;
    }

    const int p = x;   // 32-kv pair index
    unsigned short* base =
        ws + ((size_t)((b * NKV_ + kvh) * (T_ / 32) + p)) * PAIR_US;

    // K: 512 tasks = 2 tiles x 4 c x 64 lanes
    #pragma unroll
    for (int it = 0; it < 2; ++it) {
        int task = tid + it * 256;
        int tu = task >> 8, rem = task & 255;
        int c = rem >> 6, l = rem & 63;
        int qd = l >> 4, ln = l & 15;
        int kvrow = p * 32 + tu * 16 + ln;
        const float* kp = kg + (((size_t)(b * T_ + kvrow)) * NKV_ + kvh) * D_ + c * 32 + qd * 8;
        H8 hu;
        #pragma unroll
        for (int j = 0; j < 8; ++j) hu.h[j] = (_Float16)kp[j];
        *(f16x8*)(base + tu * 2048 + (c * 64 + l) * 8) = hu.v;
    }
    // V: 512 tasks = 8 subs x 64 lanes
    #pragma unroll
    for (int it = 0; it < 2; ++it) {
        int task = tid + it * 256;
        int sub = task >> 6, l = task & 63;
        int qd = l >> 4, ln = l & 15;
        U8 pk;
        #pragma unroll
        for (int j = 0; j < 8; ++j) {
            int kv = p * 32 + qd * 8 + j;
            pk.us[j] = f2bf(vg[(((size_t)(b * T_ + kv)) * NKV_ + kvh) * D_ + sub * 16 + ln]);
        }
        *(bf16x8*)(base + 4096 + (sub * 64 + l) * 8) = pk.v;
    }
}

// ---------------- main attention kernel (4 independent waves/block, 32 q-rows/wave) ----------------
__global__ __launch_bounds__(256)
void attn_fwd(const float* __restrict__ qg,
              const int* __restrict__ sstart,
              const unsigned short* __restrict__ ws,
              float* __restrict__ outg)
{
    const int tid  = threadIdx.x;
    const int wave = tid >> 6;
    const int lane = tid & 63;
    const int qd   = lane >> 4;
    const int ln   = lane & 15;

    const int kvh  = blockIdx.x;             // kv head; 4 waves = its 4 q-heads
    const int head = kvh * 4 + wave;
    const int chunk = (int)gridDim.y - 1 - (int)blockIdx.y;   // heavy-first
    const int b    = blockIdx.z;
    const int t0   = chunk * 32;

    const unsigned short* wsbase =
        ws + ((size_t)((b * NKV_ + kvh) * (T_ / 32))) * PAIR_US + lane * 8;

    // K fragments of one 16-kv tile s: 4x f16x8 (16 VGPR)
#define LOADK(KB, s) do {                                                      \
        const unsigned short* _tb =                                            \
            wsbase + (size_t)((s) >> 1) * PAIR_US + ((s) & 1) * 2048;          \
        _Pragma("unroll")                                                      \
        for (int _c = 0; _c < 4; ++_c)                                         \
            KB[_c] = *(const f16x8*)(_tb + _c * 512);                          \
    } while (0)

    // V fragments of pair pp: 8x bf16x8 (32 VGPR)
#define LOADV(VB, pp) do {                                                     \
        const unsigned short* _tb = wsbase + (size_t)(pp) * PAIR_US + 4096;    \
        _Pragma("unroll")                                                      \
        for (int _s = 0; _s < 8; ++_s)                                         \
            VB[_s] = *(const bf16x8*)(_tb + _s * 512);                         \
    } while (0)

    // QK for one 16-row group vs one 16-kv tile (base kv = S0V).
    // Lane(qd,ln): S[r] = S[kv=S0V+qd*4+r][qrow=ln]. Branchless mask+exp2,
    // stash P as 2 packed-bf16 words (W0 = p0,p1 ; W1 = p2,p3).
#define QKG(KB, QH, QL, LL, RS_L, TROW_L, S0V, W0, W1) do {                    \
        f32x4 S = {0.f, 0.f, 0.f, 0.f};                                        \
        __builtin_amdgcn_s_setprio(1);                                         \
        _Pragma("unroll")                                                      \
        for (int c = 0; c < 4; ++c) {                                          \
            S = __builtin_amdgcn_mfma_f32_16x16x32_f16(KB[c], QH[c], S,0,0,0); \
            S = __builtin_amdgcn_mfma_f32_16x16x32_f16(KB[c], QL[c], S,0,0,0); \
        }                                                                      \
        __builtin_amdgcn_s_setprio(0);                                         \
        float p[4];                                                            \
        _Pragma("unroll")                                                      \
        for (int r = 0; r < 4; ++r) {                                          \
            int kv = (S0V) + qd * 4 + r;                                       \
            float sv = (kv >= (RS_L) && kv <= (TROW_L)) ? S[r] : MASKV;        \
            p[r] = exp2f(sv);                                                  \
        }                                                                      \
        LL += (p[0] + p[1]) + (p[2] + p[3]);                                   \
        PKW _w0, _w1;                                                          \
        _w0.h = (bf16x2){(__bf16)p[0], (__bf16)p[1]};                          \
        _w1.h = (bf16x2){(__bf16)p[2], (__bf16)p[3]};                          \
        W0 = _w0.u; W1 = _w1.u;                                                \
    } while (0)

    // PV for one group over a 32-kv pair: R8-verified permlane recombine
    // (wA = low tile kv qd*4+r, wB = high tile kv 16+qd*4+r), then 8x K=32 MFMA.
#define PVG(WA0, WA1, WB0, WB1, VB, OO) do {                                   \
        unsigned int w0 = WA0, w1 = WA1, w2 = WB0, w3 = WB1;                   \
        pl32swap(w0, w2); pl32swap(w1, w3);                                    \
        pl16swap(w0, w2); pl16swap(w1, w3);                                    \
        PA4 pw; pw.u[0] = w0; pw.u[1] = w1; pw.u[2] = w2; pw.u[3] = w3;        \
        bf16x8 pa = pw.v;                                                      \
        __builtin_amdgcn_s_setprio(1);                                         \
        _Pragma("unroll")                                                      \
        for (int sub = 0; sub < 8; ++sub)                                      \
            OO[sub] = __builtin_amdgcn_mfma_f32_16x16x32_bf16(pa, VB[sub], OO[sub],0,0,0); \
        __builtin_amdgcn_s_setprio(0);                                         \
    } while (0)

    // both groups, one 16-kv tile s -> stash A or B
#define QK2(KB, s, WG00, WG01, WG10, WG11) do {                                \
        const int _s0 = (s) * 16;                                              \
        QKG(KB, qh0, ql0, l0, rs0_l, trow0_l, _s0, WG00, WG01);                \
        QKG(KB, qh1, ql1, l1, rs1_l, trow1_l, _s0, WG10, WG11);                \
    } while (0)

    // ---- preload Q fragments for both 16-row groups, scaled by log2(e), fp16 hi/lo ----
    f16x8 qh0[4], ql0[4], qh1[4], ql1[4];
    #pragma unroll
    for (int g = 0; g < 2; ++g) {
        const float* qrow =
            qg + (((size_t)(b * T_ + (t0 + g * 16 + ln)) * NQ_) + head) * D_;
        #pragma unroll
        for (int c = 0; c < 4; ++c) {
            float4 a  = *(const float4*)(qrow + c * 32 + qd * 8);
            float4 b2 = *(const float4*)(qrow + c * 32 + qd * 8 + 4);
            float xs[8] = {a.x, a.y, a.z, a.w, b2.x, b2.y, b2.z, b2.w};
            H8 hu, lu;
            #pragma unroll
            for (int jj = 0; jj < 8; ++jj) {
                float x = xs[jj] * LOG2E;
                _Float16 h = (_Float16)x;
                hu.h[jj] = h;
                lu.h[jj] = (_Float16)(x - (float)h);
            }
            if (g == 0) { qh0[c] = hu.v; ql0[c] = lu.v; }
            else        { qh1[c] = hu.v; ql1[c] = lu.v; }
        }
    }

    // ---- per-lane row info for both groups ----
    const int trow0_l = t0 + ln;
    const int trow1_l = t0 + 16 + ln;
    const int rs0_l   = sstart[b * T_ + trow0_l];
    const int rs1_l   = sstart[b * T_ + trow1_l];

    const int tile0   = sstart[b * T_ + t0] >> 4;  // 16-kv units, wave-uniform (min row)
    const int n_tiles = 2 * chunk + 2;             // even; causal: tiles 0..2chunk+1

    f32x4 O0[8], O1[8];
    #pragma unroll
    for (int k = 0; k < 8; ++k) {
        O0[k] = (f32x4){0.f, 0.f, 0.f, 0.f};
        O1[k] = (f32x4){0.f, 0.f, 0.f, 0.f};
    }
    float l0 = 0.f, l1 = 0.f;

    f16x8  kA[4], kB_[4];
    bf16x8 vP[8];
    unsigned int a00, a01, a10, a11;   // stash: group0/1 words of low tile
    unsigned int b00, b01, b10, b11;   // stash: high tile

    int t = tile0 & ~1;                // even start; extra half-tile is seg-masked (p=0)
    LOADK(kA, t);
    LOADK(kB_, t + 1);
    LOADV(vP, t >> 1);
    __builtin_amdgcn_sched_barrier(0);

    while (t + 2 < n_tiles) {
        QK2(kA, t, a00, a01, a10, a11);
        LOADK(kA, t + 2);                       // prefetch next pair's low K
        __builtin_amdgcn_sched_barrier(0);
        QK2(kB_, t + 1, b00, b01, b10, b11);
        LOADK(kB_, t + 3);                      // prefetch next pair's high K
        __builtin_amdgcn_sched_barrier(0);
        PVG(a00, a01, b00, b01, vP, O0);
        PVG(a10, a11, b10, b11, vP, O1);
        LOADV(vP, (t >> 1) + 1);                // prefetch next pair's V
        __builtin_amdgcn_sched_barrier(0);
        t += 2;
    }
    // final pair (no prefetch)
    QK2(kA, t, a00, a01, a10, a11);
    QK2(kB_, t + 1, b00, b01, b10, b11);
    PVG(a00, a01, b00, b01, vP, O0);
    PVG(a10, a11, b10, b11, vP, O1);

    // ---- epilogue per group: reduce l across qd, redistribute, store ----
    #pragma unroll
    for (int g = 0; g < 2; ++g) {
        float l = (g == 0) ? l0 : l1;
        l += __shfl_xor(l, 16);
        l += __shfl_xor(l, 32);
        const float invl = 1.0f / l;        // per lane: denom for q-row = g*16+ln
        int trow[4];
        float inv[4];
        #pragma unroll
        for (int r = 0; r < 4; ++r) {
            trow[r] = t0 + g * 16 + qd * 4 + r;
            inv[r]  = __shfl(invl, qd * 4 + r);  // lane (qd*4+r) holds row's denom
        }
        #pragma unroll
        for (int sub = 0; sub < 8; ++sub) {
            #pragma unroll
            for (int r = 0; r < 4; ++r) {
                float ov = (g == 0) ? O0[sub][r] : O1[sub][r];
                outg[(((size_t)(b * T_ + trow[r]) * NQ_) + head) * D_ + sub * 16 + ln] =
                    ov * inv[r];
            }
        }
    }

#undef LOADK
#undef LOADV
#undef QKG
#undef PVG
#undef QK2
}

// ---------------- fallback (no-ws path) ----------------
#define KSTR 136
#define VSTR 40
#define PSTR 40
static __device__ __forceinline__ float bf2f(unsigned short h) {
    union { unsigned int u; float f; } c; c.u = (unsigned int)h << 16; return c.f;
}
__global__ __launch_bounds__(256)
void attn_fwd_fb(const float* __restrict__ qg,
                 const float* __restrict__ kg,
                 const float* __restrict__ vg,
                 const int* __restrict__ seg,
                 float* __restrict__ outg)
{
    __shared__ unsigned short sKh[32 * KSTR];
    __shared__ unsigned short sKl[32 * KSTR];
    __shared__ unsigned short sVt[128 * VSTR];
    __shared__ unsigned short sP[4][16 * PSTR];

    const int tid  = threadIdx.x;
    const int wave = tid >> 6;
    const int lane = tid & 63;
    const int qd   = lane >> 4;
    const int ln   = lane & 15;
    const int t0   = ((int)gridDim.x - 1 - (int)blockIdx.x) * 64;
    const int head = blockIdx.y;
    const int kvh  = head >> 2;
    const int b    = blockIdx.z;

    bf16x8 qh[4], ql[4];
    {
        const float* qrow =
            qg + (((size_t)(b * T_ + (t0 + wave * 16 + ln)) * NQ_) + head) * D_;
        #pragma unroll
        for (int c = 0; c < 4; ++c) {
            float4 a  = *(const float4*)(qrow + c * 32 + qd * 8);
            float4 b2 = *(const float4*)(qrow + c * 32 + qd * 8 + 4);
            float xs[8] = {a.x, a.y, a.z, a.w, b2.x, b2.y, b2.z, b2.w};
            U8 hu, lu;
            #pragma unroll
            for (int j = 0; j < 8; ++j) {
                unsigned short h = f2bf(xs[j]);
                hu.us[j] = h;
                lu.us[j] = f2bf(xs[j] - bf2f(h));
            }
            qh[c] = hu.v; ql[c] = lu.v;
        }
    }
    const int* sb = seg + (size_t)b * T_;
    int qseg[4];
    #pragma unroll
    for (int r = 0; r < 4; ++r) qseg[r] = sb[t0 + wave * 16 + qd * 4 + r];
    int tile0;
    {
        int target = sb[t0];
        int lo = 0, hi = t0;
        while (lo < hi) { int mid = (lo + hi) >> 1; if (sb[mid] < target) lo = mid + 1; else hi = mid; }
        tile0 = lo >> 5;
    }
    f32x4 O[8];
    #pragma unroll
    for (int i = 0; i < 8; ++i) O[i] = (f32x4){0.f, 0.f, 0.f, 0.f};
    float m_prev[4], l_lane[4];
    #pragma unroll
    for (int r = 0; r < 4; ++r) { m_prev[r] = MASKV; l_lane[r] = 0.f; }
    const int n_tiles = t0 / 32 + 2;

    for (int tile = tile0; tile < n_tiles; ++tile) {
        const int s0 = tile * 32;
        __syncthreads();
        #pragma unroll
        for (int it = 0; it < 2; ++it) {
            int task = tid + it * 256;
            int r = task >> 4, d = (task & 15) * 8;
            const float* kp = kg + (((size_t)(b * T_ + s0 + r) * NKV_) + kvh) * D_ + d;
            float4 a  = *(const float4*)(kp);
            float4 b2 = *(const float4*)(kp + 4);
            float xs[8] = {a.x, a.y, a.z, a.w, b2.x, b2.y, b2.z, b2.w};
            U8 hu, lu;
            #pragma unroll
            for (int j = 0; j < 8; ++j) {
                unsigned short h = f2bf(xs[j]);
                hu.us[j] = h;
                lu.us[j] = f2bf(xs[j] - bf2f(h));
            }
            *(bf16x8*)(sKh + r * KSTR + d) = hu.v;
            *(bf16x8*)(sKl + r * KSTR + d) = lu.v;
        }
        #pragma unroll
        for (int it = 0; it < 2; ++it) {
            int task = tid + it * 256;
            int d = task & 127, sg = task >> 7;
            const float* vp = vg + (((size_t)(b * T_ + s0 + sg * 8) * NKV_) + kvh) * D_ + d;
            U8 pk;
            #pragma unroll
            for (int j = 0; j < 8; ++j) pk.us[j] = f2bf(vp[j * (NKV_ * D_)]);
            *(bf16x8*)(sVt + d * VSTR + sg * 8) = pk.v;
        }
        __syncthreads();

        f32x4 S0 = {0.f,0.f,0.f,0.f}, S1 = {0.f,0.f,0.f,0.f};
        #pragma unroll
        for (int c = 0; c < 4; ++c) {
            bf16x8 kh0 = *(const bf16x8*)(sKh + ln * KSTR + c * 32 + qd * 8);
            bf16x8 kh1 = *(const bf16x8*)(sKh + (16 + ln) * KSTR + c * 32 + qd * 8);
            bf16x8 kl0 = *(const bf16x8*)(sKl + ln * KSTR + c * 32 + qd * 8);
            bf16x8 kl1 = *(const bf16x8*)(sKl + (16 + ln) * KSTR + c * 32 + qd * 8);
            S0 = __builtin_amdgcn_mfma_f32_16x16x32_bf16(qh[c], kh0, S0, 0, 0, 0);
            S1 = __builtin_amdgcn_mfma_f32_16x16x32_bf16(qh[c], kh1, S1, 0, 0, 0);
            S0 = __builtin_amdgcn_mfma_f32_16x16x32_bf16(qh[c], kl0, S0, 0, 0, 0);
            S1 = __builtin_amdgcn_mfma_f32_16x16x32_bf16(qh[c], kl1, S1, 0, 0, 0);
            S0 = __builtin_amdgcn_mfma_f32_16x16x32_bf16(ql[c], kh0, S0, 0, 0, 0);
            S1 = __builtin_amdgcn_mfma_f32_16x16x32_bf16(ql[c], kh1, S1, 0, 0, 0);
        }
        const int ks0 = sb[s0 + ln];
        const int ks1 = sb[s0 + 16 + ln];
        float p0[4], p1[4], alpha[4];
        #pragma unroll
        for (int r = 0; r < 4; ++r) {
            const int trow = t0 + wave * 16 + qd * 4 + r;
            float s0v = ((s0 + ln <= trow) && (ks0 == qseg[r])) ? S0[r] : MASKV;
            float s1v = ((s0 + 16 + ln <= trow) && (ks1 == qseg[r])) ? S1[r] : MASKV;
            float mx = fmaxf(s0v, s1v);
            mx = fmaxf(mx, __shfl_xor(mx, 1));
            mx = fmaxf(mx, __shfl_xor(mx, 2));
            mx = fmaxf(mx, __shfl_xor(mx, 4));
            mx = fmaxf(mx, __shfl_xor(mx, 8));
            const float mn = fmaxf(m_prev[r], mx);
            alpha[r] = __expf(m_prev[r] - mn);
            p0[r] = __expf(s0v - mn);
            p1[r] = __expf(s1v - mn);
            l_lane[r] = alpha[r] * l_lane[r] + p0[r] + p1[r];
            m_prev[r] = mn;
        }
        #pragma unroll
        for (int i = 0; i < 8; ++i) {
            O[i][0] *= alpha[0]; O[i][1] *= alpha[1];
            O[i][2] *= alpha[2]; O[i][3] *= alpha[3];
        }
        {
            unsigned short* pw = sP[wave] + (qd * 4) * PSTR + ln;
            #pragma unroll
            for (int r = 0; r < 4; ++r) {
                pw[r * PSTR]      = f2bf(p0[r]);
                pw[r * PSTR + 16] = f2bf(p1[r]);
            }
        }
        asm volatile("s_waitcnt lgkmcnt(0)" ::: "memory");
        bf16x8 pa = *(const bf16x8*)(sP[wave] + ln * PSTR + qd * 8);
        #pragma unroll
        for (int sub = 0; sub < 8; ++sub) {
            bf16x8 bv = *(const bf16x8*)(sVt + (sub * 16 + ln) * VSTR + qd * 8);
            O[sub] = __builtin_amdgcn_mfma_f32_16x16x32_bf16(pa, bv, O[sub], 0, 0, 0);
        }
    }
    float inv[4];
    #pragma unroll
    for (int r = 0; r < 4; ++r) {
        float l = l_lane[r];
        l += __shfl_xor(l, 1);
        l += __shfl_xor(l, 2);
        l += __shfl_xor(l, 4);
        l += __shfl_xor(l, 8);
        inv[r] = 1.0f / l;
    }
    #pragma unroll
    for (int sub = 0; sub < 8; ++sub) {
        #pragma unroll
        for (int r = 0; r < 4; ++r) {
            const int trow = t0 + wave * 16 + qd * 4 + r;
            outg[(((size_t)(b * T_ + trow) * NQ_) + head) * D_ + sub * 16 + ln] =
                O[sub][r] * inv[r];
        }
    }
}

extern "C" void kernel_launch(void* const* d_in, const int* in_sizes, int n_in,
                              void* d_out, int out_size, void* d_ws, size_t ws_size,
                              hipStream_t stream) {
    const float* q  = (const float*)d_in[0];
    const float* k  = (const float*)d_in[1];
    const float* v  = (const float*)d_in[2];
    const int*   sg = (const int*)d_in[3];
    float*       o  = (float*)d_out;
    if (ws_size >= WS_NEED) {
        unsigned short* ws = (unsigned short*)d_ws;
        int* sstart = (int*)((char*)d_ws + WS_TILES_BYTES);
        prep<<<dim3(T_ / 32 + 1, NKV_, B_), dim3(256), 0, stream>>>(k, v, sg, ws, sstart);
        attn_fwd<<<dim3(NKV_, T_ / 32, B_), dim3(256), 0, stream>>>(q, sstart, ws, o);
    } else {
        attn_fwd_fb<<<dim3(T_ / 64, NQ_, B_), dim3(256), 0, stream>>>(q, k, v, sg, o);
    }
}